// Round 3
// baseline (1596.040 us; speedup 1.0000x reference)
//
#include <hip/hip_runtime.h>
#include <hip/hip_bf16.h>

// ---------------------------------------------------------------------------
// Mamba encoder fwd: B=2, L=1024, D=512, E=1024, N=16, R=32, 6 layers.
// Inputs fp32 (probe-confirmed; dynamic probe kept as insurance).
// Output fp32 (reference output dtype is jnp.float32).
// GEMMs: split-bf16 MFMA (hi/lo, 3 MFMAs per product) -> ~fp32 accuracy.
// ---------------------------------------------------------------------------

typedef __attribute__((ext_vector_type(8))) short bf16x8;
typedef __attribute__((ext_vector_type(4))) float f32x4;

__device__ __forceinline__ float bf2f(unsigned short u) {
    unsigned int x = ((unsigned int)u) << 16;
    return __builtin_bit_cast(float, x);
}
__device__ __forceinline__ unsigned short f2bf(float f) {
    __hip_bfloat16 h = __float2bfloat16(f);   // RNE
    return __builtin_bit_cast(unsigned short, h);
}
// dynamic-dtype scalar load: isbf ? bf16[i] : f32[i]
__device__ __forceinline__ float ldin(const void* p, size_t i, int isbf) {
    return isbf ? bf2f(((const unsigned short*)p)[i]) : ((const float*)p)[i];
}
__device__ __forceinline__ float softplus_f(float x) {
    return (x > 20.f) ? x : log1pf(__expf(x));
}
// split x into bf16 hi + bf16 lo (x - hi is exact in fp32)
__device__ __forceinline__ void split2(float x, unsigned short& h, unsigned short& l) {
    h = f2bf(x);
    l = f2bf(x - bf2f(h));
}

// ------------------------- dtype probe (D == 1.0) ---------------------------
__global__ void dtype_probe(const void* __restrict__ D, int* __restrict__ flag) {
    // fp32 1.0 -> 0x3F800000 ; bf16 {1.0,1.0} -> 0x3F803F80
    *flag = (*(const unsigned int*)D == 0x3F800000u) ? 0 : 1;
}

// ------------------------- x -> fp32 h (layer 0) ----------------------------
__global__ __launch_bounds__(256) void cvt_in(const void* __restrict__ x,
                                              const int* __restrict__ flag,
                                              float* __restrict__ h, int n) {
    const int isbf = *flag;
    int g = blockIdx.x * 256 + threadIdx.x;
    if (g < n) h[g] = ldin(x, g, isbf);
}

// --------------------------- GEMM: C = A * W^T ------------------------------
// A: M x K fp32 (activations), row stride lda.  W: N x K dyn-dtype + woff.
// C: row-major M x N fp32.  bias dyn-dtype (len N) + boff.
// ACT: 0 = none, 1 = softplus.
// Split-bf16: acc += Ah*Wh + Ah*Wl + Al*Wh  (~2^-18 relative error).
// Tile 64x64, BK=32, 256 threads (4 waves, 2x2 wave grid, each 2x2 mfma).
template <int ACT>
__global__ __launch_bounds__(256) void gemm_bt(
    const float* __restrict__ A, int lda,
    const void* __restrict__ Wv, long woff,
    float* __restrict__ Cf,
    const void* __restrict__ bias, long boff,
    const int* __restrict__ flag,
    int N, int K)
{
    const int isbf = *flag;
    __shared__ unsigned short As[2][64][40];   // [hi/lo][row][col], +8 pad
    __shared__ unsigned short Ws[2][64][40];

    const int m0 = blockIdx.x * 64, n0 = blockIdx.y * 64;
    const int t = threadIdx.x;
    const int lane = t & 63, wave = t >> 6;
    const int wm = (wave & 1) * 32, wn = (wave >> 1) * 32;
    const int srow = t >> 2, scol = (t & 3) * 8;

    f32x4 acc[2][2] = {};

    for (int k0 = 0; k0 < K; k0 += 32) {
        __syncthreads();
        {   // A staging: fp32 -> bf16 hi/lo
            const float* ap = A + (size_t)(m0 + srow) * lda + k0 + scol;
            float4 x0 = *(const float4*)ap;
            float4 x1 = *(const float4*)(ap + 4);
            float v[8] = {x0.x, x0.y, x0.z, x0.w, x1.x, x1.y, x1.z, x1.w};
            unsigned short hs[8], ls[8];
#pragma unroll
            for (int j = 0; j < 8; ++j) split2(v[j], hs[j], ls[j]);
#pragma unroll
            for (int j = 0; j < 8; ++j) {
                As[0][srow][scol + j] = hs[j];
                As[1][srow][scol + j] = ls[j];
            }
        }
        if (isbf) { // W already bf16: hi = data, lo = 0
            const unsigned short* wp =
                (const unsigned short*)Wv + woff + (size_t)(n0 + srow) * K + k0 + scol;
            uint4 vw = *(const uint4*)wp;
            *(uint4*)(&Ws[0][srow][scol]) = vw;
            uint4 z; z.x = z.y = z.z = z.w = 0;
            *(uint4*)(&Ws[1][srow][scol]) = z;
        } else {    // W fp32 -> bf16 hi/lo
            const float* wp = (const float*)Wv + woff + (size_t)(n0 + srow) * K + k0 + scol;
            float4 x0 = *(const float4*)wp;
            float4 x1 = *(const float4*)(wp + 4);
            float v[8] = {x0.x, x0.y, x0.z, x0.w, x1.x, x1.y, x1.z, x1.w};
            unsigned short hs[8], ls[8];
#pragma unroll
            for (int j = 0; j < 8; ++j) split2(v[j], hs[j], ls[j]);
#pragma unroll
            for (int j = 0; j < 8; ++j) {
                Ws[0][srow][scol + j] = hs[j];
                Ws[1][srow][scol + j] = ls[j];
            }
        }
        __syncthreads();

        const int fm = lane & 15, fk = (lane >> 4) * 8;
        bf16x8 a0h = *(const bf16x8*)(&As[0][wm + fm][fk]);
        bf16x8 a1h = *(const bf16x8*)(&As[0][wm + 16 + fm][fk]);
        bf16x8 w0h = *(const bf16x8*)(&Ws[0][wn + fm][fk]);
        bf16x8 w1h = *(const bf16x8*)(&Ws[0][wn + 16 + fm][fk]);
        bf16x8 a0l = *(const bf16x8*)(&As[1][wm + fm][fk]);
        bf16x8 a1l = *(const bf16x8*)(&As[1][wm + 16 + fm][fk]);
        bf16x8 w0l = *(const bf16x8*)(&Ws[1][wn + fm][fk]);
        bf16x8 w1l = *(const bf16x8*)(&Ws[1][wn + 16 + fm][fk]);

        acc[0][0] = __builtin_amdgcn_mfma_f32_16x16x32_bf16(a0h, w0h, acc[0][0], 0, 0, 0);
        acc[0][1] = __builtin_amdgcn_mfma_f32_16x16x32_bf16(a0h, w1h, acc[0][1], 0, 0, 0);
        acc[1][0] = __builtin_amdgcn_mfma_f32_16x16x32_bf16(a1h, w0h, acc[1][0], 0, 0, 0);
        acc[1][1] = __builtin_amdgcn_mfma_f32_16x16x32_bf16(a1h, w1h, acc[1][1], 0, 0, 0);
        acc[0][0] = __builtin_amdgcn_mfma_f32_16x16x32_bf16(a0h, w0l, acc[0][0], 0, 0, 0);
        acc[0][1] = __builtin_amdgcn_mfma_f32_16x16x32_bf16(a0h, w1l, acc[0][1], 0, 0, 0);
        acc[1][0] = __builtin_amdgcn_mfma_f32_16x16x32_bf16(a1h, w0l, acc[1][0], 0, 0, 0);
        acc[1][1] = __builtin_amdgcn_mfma_f32_16x16x32_bf16(a1h, w1l, acc[1][1], 0, 0, 0);
        acc[0][0] = __builtin_amdgcn_mfma_f32_16x16x32_bf16(a0l, w0h, acc[0][0], 0, 0, 0);
        acc[0][1] = __builtin_amdgcn_mfma_f32_16x16x32_bf16(a0l, w1h, acc[0][1], 0, 0, 0);
        acc[1][0] = __builtin_amdgcn_mfma_f32_16x16x32_bf16(a1l, w0h, acc[1][0], 0, 0, 0);
        acc[1][1] = __builtin_amdgcn_mfma_f32_16x16x32_bf16(a1l, w1h, acc[1][1], 0, 0, 0);
    }

    const int col = lane & 15, rb = (lane >> 4) * 4;
#pragma unroll
    for (int mi = 0; mi < 2; ++mi)
#pragma unroll
        for (int ni = 0; ni < 2; ++ni)
#pragma unroll
            for (int r = 0; r < 4; ++r) {
                int gm = m0 + wm + mi * 16 + rb + r;
                int gn = n0 + wn + ni * 16 + col;
                float v = acc[mi][ni][r];
                if (bias) v += ldin(bias, boff + gn, isbf);
                if (ACT == 1) v = softplus_f(v);
                Cf[(size_t)gm * N + gn] = v;
            }
}

// --------------------------- RMSNorm(h + pos) -------------------------------
__global__ __launch_bounds__(256) void rmsnorm_k(
    const float* __restrict__ h, const void* __restrict__ pos,
    const void* __restrict__ nw, const int* __restrict__ flag,
    float* __restrict__ xn)
{
    const int isbf = *flag;
    const int row = blockIdx.x;           // T = 2048 rows of 512
    const int t = threadIdx.x;
    const size_t base = (size_t)row * 512;
    float v0 = h[base + t]       + ldin(pos, base + t, isbf);
    float v1 = h[base + 256 + t] + ldin(pos, base + 256 + t, isbf);
    float ss = v0 * v0 + v1 * v1;
#pragma unroll
    for (int o = 32; o; o >>= 1) ss += __shfl_xor(ss, o, 64);
    __shared__ float sw[4];
    if ((t & 63) == 0) sw[t >> 6] = ss;
    __syncthreads();
    float tot = sw[0] + sw[1] + sw[2] + sw[3];
    float sc = rsqrtf(tot * (1.0f / 512.0f) + 1.1920929e-07f);
    xn[base + t]       = v0 * sc * ldin(nw, t, isbf);
    xn[base + 256 + t] = v1 * sc * ldin(nw, 256 + t, isbf);
}

// ------------------- causal depthwise conv (k=4) + SiLU ---------------------
__global__ __launch_bounds__(256) void conv_silu_k(
    const float* __restrict__ xz,
    const void* __restrict__ cw, long cwoff,
    const void* __restrict__ cb, long cboff,
    const int* __restrict__ flag,
    float* __restrict__ xi)
{
    const int isbf = *flag;
    int g = blockIdx.x * 256 + threadIdx.x;   // T*E = 2M
    int e = g & 1023;
    int l = (g >> 10) & 1023;
    int b = g >> 20;
    float acc = ldin(cb, cboff + e, isbf);
#pragma unroll
    for (int k = 0; k < 4; ++k) {
        int ls = l - 3 + k;
        if (ls >= 0)
            acc += ldin(cw, cwoff + e * 4 + k, isbf) *
                   xz[((size_t)(b * 1024 + ls)) * 2048 + e];
    }
    acc = acc / (1.f + __expf(-acc));         // SiLU
    xi[g] = acc;
}

// --------------------- selective scan, chunked (16 x 64) --------------------
// thread g = n + 16*c + 256*e + 262144*b
__global__ __launch_bounds__(256) void scan_stage1(
    const float* __restrict__ dtp, const float* __restrict__ u,
    const float* __restrict__ dbc,
    const void* __restrict__ alog, long aoff, const int* __restrict__ flag,
    float* __restrict__ P, float* __restrict__ S)
{
    const int isbf = *flag;
    int g = blockIdx.x * 256 + threadIdx.x;   // 524288
    int n = g & 15, c = (g >> 4) & 15, e = (g >> 8) & 1023, b = g >> 18;
    float Aen = -__expf(ldin(alog, aoff + e * 16 + n, isbf));
    float Pr = 1.f, Sv = 0.f;
    int t0 = b * 1024 + c * 64;
    for (int i = 0; i < 64; ++i) {
        int t = t0 + i;
        float d = dtp[(size_t)t * 1024 + e];
        float a = __expf(d * Aen);
        Sv = a * Sv + d * u[(size_t)t * 1024 + e] * dbc[t * 64 + 32 + n];
        Pr *= a;
    }
    P[g] = Pr;
    S[g] = Sv;
}

// cross-chunk combine IN PLACE: PH holds P on entry, H0 (chunk-start state)
// on exit.  One thread owns the whole c-sequence -> read-then-write is safe.
__global__ __launch_bounds__(256) void scan_stage2(
    float* __restrict__ PH, const float* __restrict__ S)
{
    int g = blockIdx.x * 256 + threadIdx.x;   // 32768: n + 16*e + 16384*b
    int n = g & 15, e = (g >> 4) & 1023, b = g >> 14;
    size_t base = ((size_t)(b * 1024 + e)) * 256 + n;
    float H = 0.f;
#pragma unroll
    for (int c = 0; c < 16; ++c) {
        size_t idx = base + (size_t)c * 16;
        float p = PH[idx], s = S[idx];
        PH[idx] = H;
        H = p * H + s;
    }
}

// final sweep: recompute h in-chunk from H0, y = sum_n C*h, +u*D, gate
__global__ __launch_bounds__(256) void scan_stage3(
    const float* __restrict__ dtp, const float* __restrict__ u,
    const float* __restrict__ dbc,
    const void* __restrict__ alog, long aoff,
    const void* __restrict__ Dv, long doff,
    const int* __restrict__ flag,
    const float* __restrict__ xz, const float* __restrict__ H0,
    float* __restrict__ yg)
{
    const int isbf = *flag;
    int g = blockIdx.x * 256 + threadIdx.x;
    int n = g & 15, c = (g >> 4) & 15, e = (g >> 8) & 1023, b = g >> 18;
    float Aen = -__expf(ldin(alog, aoff + e * 16 + n, isbf));
    float h = H0[g];
    float De = ldin(Dv, doff + e, isbf);
    int t0 = b * 1024 + c * 64;
    for (int i = 0; i < 64; ++i) {
        int t = t0 + i;
        float d = dtp[(size_t)t * 1024 + e];
        float uu = u[(size_t)t * 1024 + e];
        float a = __expf(d * Aen);
        h = a * h + d * uu * dbc[t * 64 + 32 + n];
        float p = h * dbc[t * 64 + 48 + n];
        p += __shfl_xor(p, 1, 64);
        p += __shfl_xor(p, 2, 64);
        p += __shfl_xor(p, 4, 64);
        p += __shfl_xor(p, 8, 64);
        if (n == 0) {
            float z = xz[(size_t)t * 2048 + 1024 + e];
            float sz = z / (1.f + __expf(-z));
            yg[(size_t)t * 1024 + e] = (p + uu * De) * sz;
        }
    }
}

// ------------------------------- launcher -----------------------------------
extern "C" void kernel_launch(void* const* d_in, const int* in_sizes, int n_in,
                              void* d_out, int out_size, void* d_ws, size_t ws_size,
                              hipStream_t stream)
{
    const void* x    = d_in[0];
    const void* pos  = d_in[1];
    const void* nw   = d_in[2];
    const void* ipw  = d_in[3];   // (6,2048,512)
    const void* cw   = d_in[4];   // (6,1024,4)
    const void* cb   = d_in[5];   // (6,1024)
    const void* xpw  = d_in[6];   // (6,64,1024)
    const void* dtw  = d_in[7];   // (6,1024,32)
    const void* dtb  = d_in[8];   // (6,1024)
    const void* alog = d_in[9];   // (6,1024,16)
    const void* Dw   = d_in[10];  // (6,1024)
    const void* ow   = d_in[11];  // (6,512,1024)

    const size_t MB = 1u << 20;
    char* w = (char*)d_ws;
    float* h   = (float*)(w);                        // 4 MB   (T,512)
    float* xz  = (float*)(w + 4 * MB);               // 16 MB  (T,2048)
    float* xi  = (float*)(w + 20 * MB);              // 8 MB   (T,1024)
    float* dtf = (float*)(w + 28 * MB);              // 8 MB   (T,1024)
    float* dbc = (float*)(w + 36 * MB);              // 0.5 MB (T,64)
    float* P   = (float*)(w + 36 * MB + 512 * 1024); // 2 MB   (also H0)
    float* S   = (float*)(w + 38 * MB + 512 * 1024); // 2 MB
    float* xn  = (float*)(w + 40 * MB + 512 * 1024); // 4 MB   (T,512)
    float* yg  = (float*)(w + 40 * MB + 512 * 1024); // 8 MB, aliases xn (disjoint lifetime)
    int*  flag = (int*)  (w + 48 * MB + 512 * 1024); // 4 B

    dtype_probe<<<1, 1, 0, stream>>>(Dw, flag);
    cvt_in<<<4096, 256, 0, stream>>>(x, flag, h, 2048 * 512);

    for (int l = 0; l < 6; ++l) {
        rmsnorm_k<<<2048, 256, 0, stream>>>(h, pos, nw, flag, xn);
        // in_proj: (T,512) x (2048,512)^T -> xz (T,2048)
        gemm_bt<0><<<dim3(32, 32), 256, 0, stream>>>(
            xn, 512, ipw, (long)l * 2048 * 512, xz, nullptr, 0, flag, 2048, 512);
        conv_silu_k<<<8192, 256, 0, stream>>>(xz, cw, (long)l * 4096, cb, (long)l * 1024,
                                              flag, xi);
        // x_proj: (T,1024) x (64,1024)^T -> dbc (T,64)
        gemm_bt<0><<<dim3(32, 1), 256, 0, stream>>>(
            xi, 1024, xpw, (long)l * 64 * 1024, dbc, nullptr, 0, flag, 64, 1024);
        // dt_proj: (T,32 of 64) x (1024,32)^T + dt_b, softplus -> dtf (T,1024)
        gemm_bt<1><<<dim3(32, 16), 256, 0, stream>>>(
            dbc, 64, dtw, (long)l * 1024 * 32, dtf, dtb, (long)l * 1024,
            flag, 1024, 32);
        scan_stage1<<<2048, 256, 0, stream>>>(dtf, xi, dbc, alog, (long)l * 16384,
                                              flag, P, S);
        scan_stage2<<<128, 256, 0, stream>>>(P, S);
        scan_stage3<<<2048, 256, 0, stream>>>(dtf, xi, dbc, alog, (long)l * 16384,
                                              Dw, (long)l * 1024, flag, xz, P, yg);
        // out_proj: (T,1024) x (512,1024)^T -> h (T,512); last layer -> fp32 d_out
        float* outp = (l < 5) ? h : (float*)d_out;
        gemm_bt<0><<<dim3(32, 8), 256, 0, stream>>>(
            yg, 1024, ow, (long)l * 512 * 1024, outp, nullptr, 0, flag, 512, 1024);
    }
}

// Round 4
// 1189.733 us; speedup vs baseline: 1.3415x; 1.3415x over previous
//
#include <hip/hip_runtime.h>
#include <hip/hip_bf16.h>

// ---------------------------------------------------------------------------
// Mamba encoder fwd: B=2, L=1024, D=512, E=1024, N=16, R=32, 6 layers.
// Inputs fp32 (probe-confirmed; dynamic probe kept as insurance). Output fp32.
// GEMMs: split-bf16 MFMA (hi/lo, 3 MFMAs) -> ~fp32 accuracy.
// Scan: chunked (32 x 32), lane axis = e (coalesced), 16 states in registers.
// ---------------------------------------------------------------------------

typedef __attribute__((ext_vector_type(8))) short bf16x8;
typedef __attribute__((ext_vector_type(4))) float f32x4;

__device__ __forceinline__ float bf2f(unsigned short u) {
    unsigned int x = ((unsigned int)u) << 16;
    return __builtin_bit_cast(float, x);
}
__device__ __forceinline__ unsigned short f2bf(float f) {
    __hip_bfloat16 h = __float2bfloat16(f);   // RNE
    return __builtin_bit_cast(unsigned short, h);
}
__device__ __forceinline__ float ldin(const void* p, size_t i, int isbf) {
    return isbf ? bf2f(((const unsigned short*)p)[i]) : ((const float*)p)[i];
}
__device__ __forceinline__ float softplus_f(float x) {
    return (x > 20.f) ? x : log1pf(__expf(x));
}
__device__ __forceinline__ void split2(float x, unsigned short& h, unsigned short& l) {
    h = f2bf(x);
    l = f2bf(x - bf2f(h));
}

// ------------------------- dtype probe (D == 1.0) ---------------------------
__global__ void dtype_probe(const void* __restrict__ D, int* __restrict__ flag) {
    *flag = (*(const unsigned int*)D == 0x3F800000u) ? 0 : 1;
}

// ------------------------- x -> fp32 h (layer 0) ----------------------------
__global__ __launch_bounds__(256) void cvt_in(const void* __restrict__ x,
                                              const int* __restrict__ flag,
                                              float* __restrict__ h, int n) {
    const int isbf = *flag;
    int g = blockIdx.x * 256 + threadIdx.x;
    if (g < n) h[g] = ldin(x, g, isbf);
}

// --------------------------- GEMM: C = A * W^T ------------------------------
// Split-bf16: acc += Ah*Wh + Ah*Wl + Al*Wh.  Tile 64x64, BK=32, 256 threads.
template <int ACT>
__global__ __launch_bounds__(256) void gemm_bt(
    const float* __restrict__ A, int lda,
    const void* __restrict__ Wv, long woff,
    float* __restrict__ Cf,
    const void* __restrict__ bias, long boff,
    const int* __restrict__ flag,
    int N, int K)
{
    const int isbf = *flag;
    __shared__ unsigned short As[2][64][40];   // [hi/lo][row][col], +8 pad
    __shared__ unsigned short Ws[2][64][40];

    const int m0 = blockIdx.x * 64, n0 = blockIdx.y * 64;
    const int t = threadIdx.x;
    const int lane = t & 63, wave = t >> 6;
    const int wm = (wave & 1) * 32, wn = (wave >> 1) * 32;
    const int srow = t >> 2, scol = (t & 3) * 8;

    f32x4 acc[2][2] = {};

    for (int k0 = 0; k0 < K; k0 += 32) {
        __syncthreads();
        {   // A staging: fp32 -> bf16 hi/lo
            const float* ap = A + (size_t)(m0 + srow) * lda + k0 + scol;
            float4 x0 = *(const float4*)ap;
            float4 x1 = *(const float4*)(ap + 4);
            float v[8] = {x0.x, x0.y, x0.z, x0.w, x1.x, x1.y, x1.z, x1.w};
            unsigned short hs[8], ls[8];
#pragma unroll
            for (int j = 0; j < 8; ++j) split2(v[j], hs[j], ls[j]);
#pragma unroll
            for (int j = 0; j < 8; ++j) {
                As[0][srow][scol + j] = hs[j];
                As[1][srow][scol + j] = ls[j];
            }
        }
        if (isbf) {
            const unsigned short* wp =
                (const unsigned short*)Wv + woff + (size_t)(n0 + srow) * K + k0 + scol;
            uint4 vw = *(const uint4*)wp;
            *(uint4*)(&Ws[0][srow][scol]) = vw;
            uint4 z; z.x = z.y = z.z = z.w = 0;
            *(uint4*)(&Ws[1][srow][scol]) = z;
        } else {
            const float* wp = (const float*)Wv + woff + (size_t)(n0 + srow) * K + k0 + scol;
            float4 x0 = *(const float4*)wp;
            float4 x1 = *(const float4*)(wp + 4);
            float v[8] = {x0.x, x0.y, x0.z, x0.w, x1.x, x1.y, x1.z, x1.w};
            unsigned short hs[8], ls[8];
#pragma unroll
            for (int j = 0; j < 8; ++j) split2(v[j], hs[j], ls[j]);
#pragma unroll
            for (int j = 0; j < 8; ++j) {
                Ws[0][srow][scol + j] = hs[j];
                Ws[1][srow][scol + j] = ls[j];
            }
        }
        __syncthreads();

        const int fm = lane & 15, fk = (lane >> 4) * 8;
        bf16x8 a0h = *(const bf16x8*)(&As[0][wm + fm][fk]);
        bf16x8 a1h = *(const bf16x8*)(&As[0][wm + 16 + fm][fk]);
        bf16x8 w0h = *(const bf16x8*)(&Ws[0][wn + fm][fk]);
        bf16x8 w1h = *(const bf16x8*)(&Ws[0][wn + 16 + fm][fk]);
        bf16x8 a0l = *(const bf16x8*)(&As[1][wm + fm][fk]);
        bf16x8 a1l = *(const bf16x8*)(&As[1][wm + 16 + fm][fk]);
        bf16x8 w0l = *(const bf16x8*)(&Ws[1][wn + fm][fk]);
        bf16x8 w1l = *(const bf16x8*)(&Ws[1][wn + 16 + fm][fk]);

        acc[0][0] = __builtin_amdgcn_mfma_f32_16x16x32_bf16(a0h, w0h, acc[0][0], 0, 0, 0);
        acc[0][1] = __builtin_amdgcn_mfma_f32_16x16x32_bf16(a0h, w1h, acc[0][1], 0, 0, 0);
        acc[1][0] = __builtin_amdgcn_mfma_f32_16x16x32_bf16(a1h, w0h, acc[1][0], 0, 0, 0);
        acc[1][1] = __builtin_amdgcn_mfma_f32_16x16x32_bf16(a1h, w1h, acc[1][1], 0, 0, 0);
        acc[0][0] = __builtin_amdgcn_mfma_f32_16x16x32_bf16(a0h, w0l, acc[0][0], 0, 0, 0);
        acc[0][1] = __builtin_amdgcn_mfma_f32_16x16x32_bf16(a0h, w1l, acc[0][1], 0, 0, 0);
        acc[1][0] = __builtin_amdgcn_mfma_f32_16x16x32_bf16(a1h, w0l, acc[1][0], 0, 0, 0);
        acc[1][1] = __builtin_amdgcn_mfma_f32_16x16x32_bf16(a1h, w1l, acc[1][1], 0, 0, 0);
        acc[0][0] = __builtin_amdgcn_mfma_f32_16x16x32_bf16(a0l, w0h, acc[0][0], 0, 0, 0);
        acc[0][1] = __builtin_amdgcn_mfma_f32_16x16x32_bf16(a0l, w1h, acc[0][1], 0, 0, 0);
        acc[1][0] = __builtin_amdgcn_mfma_f32_16x16x32_bf16(a1l, w0h, acc[1][0], 0, 0, 0);
        acc[1][1] = __builtin_amdgcn_mfma_f32_16x16x32_bf16(a1l, w1h, acc[1][1], 0, 0, 0);
    }

    const int col = lane & 15, rb = (lane >> 4) * 4;
#pragma unroll
    for (int mi = 0; mi < 2; ++mi)
#pragma unroll
        for (int ni = 0; ni < 2; ++ni)
#pragma unroll
            for (int r = 0; r < 4; ++r) {
                int gm = m0 + wm + mi * 16 + rb + r;
                int gn = n0 + wn + ni * 16 + col;
                float v = acc[mi][ni][r];
                if (bias) v += ldin(bias, boff + gn, isbf);
                if (ACT == 1) v = softplus_f(v);
                Cf[(size_t)gm * N + gn] = v;
            }
}

// --------------------------- RMSNorm(h + pos) -------------------------------
__global__ __launch_bounds__(256) void rmsnorm_k(
    const float* __restrict__ h, const void* __restrict__ pos,
    const void* __restrict__ nw, const int* __restrict__ flag,
    float* __restrict__ xn)
{
    const int isbf = *flag;
    const int row = blockIdx.x;
    const int t = threadIdx.x;
    const size_t base = (size_t)row * 512;
    float v0 = h[base + t]       + ldin(pos, base + t, isbf);
    float v1 = h[base + 256 + t] + ldin(pos, base + 256 + t, isbf);
    float ss = v0 * v0 + v1 * v1;
#pragma unroll
    for (int o = 32; o; o >>= 1) ss += __shfl_xor(ss, o, 64);
    __shared__ float sw[4];
    if ((t & 63) == 0) sw[t >> 6] = ss;
    __syncthreads();
    float tot = sw[0] + sw[1] + sw[2] + sw[3];
    float sc = rsqrtf(tot * (1.0f / 512.0f) + 1.1920929e-07f);
    xn[base + t]       = v0 * sc * ldin(nw, t, isbf);
    xn[base + 256 + t] = v1 * sc * ldin(nw, 256 + t, isbf);
}

// ------------------- causal depthwise conv (k=4) + SiLU ---------------------
__global__ __launch_bounds__(256) void conv_silu_k(
    const float* __restrict__ xz,
    const void* __restrict__ cw, long cwoff,
    const void* __restrict__ cb, long cboff,
    const int* __restrict__ flag,
    float* __restrict__ xi)
{
    const int isbf = *flag;
    int g = blockIdx.x * 256 + threadIdx.x;   // T*E = 2M
    int e = g & 1023;
    int l = (g >> 10) & 1023;
    int b = g >> 20;
    float acc = ldin(cb, cboff + e, isbf);
#pragma unroll
    for (int k = 0; k < 4; ++k) {
        int ls = l - 3 + k;
        if (ls >= 0)
            acc += ldin(cw, cwoff + e * 4 + k, isbf) *
                   xz[((size_t)(b * 1024 + ls)) * 2048 + e];
    }
    acc = acc / (1.f + __expf(-acc));         // SiLU
    xi[g] = acc;
}

// --------------------- selective scan, chunked (32 x 32) --------------------
// NCH = 32 chunks of CL = 32 steps. Thread = (b, c, e); lane axis = e
// (coalesced dt/u/z/y); 16 states per thread in registers.
// P,S,H0 layout: [b][c][n][e] -> idx ((b*32+c)*16+n)*1024 + e.

__global__ __launch_bounds__(256) void scan_stage1(
    const float* __restrict__ dtp, const float* __restrict__ u,
    const float* __restrict__ dbc,
    const void* __restrict__ alog, long aoff, const int* __restrict__ flag,
    float* __restrict__ P, float* __restrict__ S)
{
    const int isbf = *flag;
    int g = blockIdx.x * 256 + threadIdx.x;   // 65536
    int e = g & 1023, c = (g >> 10) & 31, b = g >> 15;

    float Aen[16], Pn[16], Sn[16];
#pragma unroll
    for (int n = 0; n < 16; ++n) {
        Aen[n] = -__expf(ldin(alog, aoff + e * 16 + n, isbf));
        Pn[n] = 1.f; Sn[n] = 0.f;
    }
    int t0 = b * 1024 + c * 32;
    for (int i = 0; i < 32; ++i) {
        int t = t0 + i;
        float d  = dtp[(size_t)t * 1024 + e];
        float du = d * u[(size_t)t * 1024 + e];
        const float4* Bp = (const float4*)(dbc + (size_t)t * 64 + 32);
        float4 b0 = Bp[0], b1 = Bp[1], b2 = Bp[2], b3 = Bp[3];
        float Bt[16] = {b0.x,b0.y,b0.z,b0.w, b1.x,b1.y,b1.z,b1.w,
                        b2.x,b2.y,b2.z,b2.w, b3.x,b3.y,b3.z,b3.w};
#pragma unroll
        for (int n = 0; n < 16; ++n) {
            float a = __expf(d * Aen[n]);
            Sn[n] = a * Sn[n] + du * Bt[n];
            Pn[n] *= a;
        }
    }
    size_t ob = ((size_t)(b * 32 + c) * 16) * 1024 + e;
#pragma unroll
    for (int n = 0; n < 16; ++n) {
        P[ob + (size_t)n * 1024] = Pn[n];
        S[ob + (size_t)n * 1024] = Sn[n];
    }
}

// cross-chunk combine IN PLACE: PH holds P on entry, H0 on exit.
__global__ __launch_bounds__(256) void scan_stage2(
    float* __restrict__ PH, const float* __restrict__ S)
{
    int g = blockIdx.x * 256 + threadIdx.x;   // 32768: e + 1024n + 16384b
    int e = g & 1023, n = (g >> 10) & 15, b = g >> 14;
    float H = 0.f;
#pragma unroll
    for (int c = 0; c < 32; ++c) {
        size_t idx = ((size_t)(b * 32 + c) * 16 + n) * 1024 + e;
        float p = PH[idx], s = S[idx];
        PH[idx] = H;
        H = p * H + s;
    }
}

// final sweep: recompute h in-chunk from H0, y = sum_n C*h, +u*D, gate.
// Writes y IN PLACE over u (xi): each (t,e) owned by exactly one thread.
__global__ __launch_bounds__(256) void scan_stage3(
    const float* __restrict__ dtp, float* __restrict__ u,
    const float* __restrict__ dbc,
    const void* __restrict__ alog, long aoff,
    const void* __restrict__ Dv, long doff,
    const int* __restrict__ flag,
    const float* __restrict__ xz, const float* __restrict__ H0)
{
    const int isbf = *flag;
    int g = blockIdx.x * 256 + threadIdx.x;   // 65536
    int e = g & 1023, c = (g >> 10) & 31, b = g >> 15;

    float Aen[16], h[16];
    size_t ob = ((size_t)(b * 32 + c) * 16) * 1024 + e;
#pragma unroll
    for (int n = 0; n < 16; ++n) {
        Aen[n] = -__expf(ldin(alog, aoff + e * 16 + n, isbf));
        h[n] = H0[ob + (size_t)n * 1024];
    }
    float De = ldin(Dv, doff + e, isbf);
    int t0 = b * 1024 + c * 32;
    for (int i = 0; i < 32; ++i) {
        int t = t0 + i;
        float d  = dtp[(size_t)t * 1024 + e];
        float uu = u[(size_t)t * 1024 + e];
        float du = d * uu;
        const float4* Bp = (const float4*)(dbc + (size_t)t * 64 + 32);
        float4 b0 = Bp[0], b1 = Bp[1], b2 = Bp[2], b3 = Bp[3];
        float4 c0 = Bp[4], c1 = Bp[5], c2 = Bp[6], c3 = Bp[7];
        float Bt[16] = {b0.x,b0.y,b0.z,b0.w, b1.x,b1.y,b1.z,b1.w,
                        b2.x,b2.y,b2.z,b2.w, b3.x,b3.y,b3.z,b3.w};
        float Ct[16] = {c0.x,c0.y,c0.z,c0.w, c1.x,c1.y,c1.z,c1.w,
                        c2.x,c2.y,c2.z,c2.w, c3.x,c3.y,c3.z,c3.w};
        float y = 0.f;
#pragma unroll
        for (int n = 0; n < 16; ++n) {
            float a = __expf(d * Aen[n]);
            h[n] = a * h[n] + du * Bt[n];
            y += h[n] * Ct[n];
        }
        float z = xz[(size_t)t * 2048 + 1024 + e];
        float sz = z / (1.f + __expf(-z));
        u[(size_t)t * 1024 + e] = (y + uu * De) * sz;
    }
}

// ------------------------------- launcher -----------------------------------
extern "C" void kernel_launch(void* const* d_in, const int* in_sizes, int n_in,
                              void* d_out, int out_size, void* d_ws, size_t ws_size,
                              hipStream_t stream)
{
    const void* x    = d_in[0];
    const void* pos  = d_in[1];
    const void* nw   = d_in[2];
    const void* ipw  = d_in[3];   // (6,2048,512)
    const void* cw   = d_in[4];   // (6,1024,4)
    const void* cb   = d_in[5];   // (6,1024)
    const void* xpw  = d_in[6];   // (6,64,1024)
    const void* dtw  = d_in[7];   // (6,1024,32)
    const void* dtb  = d_in[8];   // (6,1024)
    const void* alog = d_in[9];   // (6,1024,16)
    const void* Dw   = d_in[10];  // (6,1024)
    const void* ow   = d_in[11];  // (6,512,1024)

    const size_t MB = 1u << 20;
    char* w = (char*)d_ws;
    float* h   = (float*)(w);                          // 4 MB   (T,512)
    float* xz  = (float*)(w + 4 * MB);                 // 16 MB  (T,2048)
    float* xi  = (float*)(w + 20 * MB);                // 8 MB   (T,1024) u then y
    float* dtf = (float*)(w + 28 * MB);                // 8 MB   (T,1024)
    float* dbc = (float*)(w + 36 * MB);                // 0.5 MB (T,64)
    float* P   = (float*)(w + 36 * MB + 512 * 1024);   // 4 MB   (also H0)
    float* S   = (float*)(w + 40 * MB + 512 * 1024);   // 4 MB
    float* xn  = (float*)(w + 44 * MB + 512 * 1024);   // 4 MB   (T,512)
    int*  flag = (int*)  (w + 48 * MB + 512 * 1024);   // 4 B (proven ws >= this)

    dtype_probe<<<1, 1, 0, stream>>>(Dw, flag);
    cvt_in<<<4096, 256, 0, stream>>>(x, flag, h, 2048 * 512);

    for (int l = 0; l < 6; ++l) {
        rmsnorm_k<<<2048, 256, 0, stream>>>(h, pos, nw, flag, xn);
        // in_proj: (T,512) x (2048,512)^T -> xz (T,2048)
        gemm_bt<0><<<dim3(32, 32), 256, 0, stream>>>(
            xn, 512, ipw, (long)l * 2048 * 512, xz, nullptr, 0, flag, 2048, 512);
        conv_silu_k<<<8192, 256, 0, stream>>>(xz, cw, (long)l * 4096, cb, (long)l * 1024,
                                              flag, xi);
        // x_proj: (T,1024) x (64,1024)^T -> dbc (T,64)
        gemm_bt<0><<<dim3(32, 1), 256, 0, stream>>>(
            xi, 1024, xpw, (long)l * 64 * 1024, dbc, nullptr, 0, flag, 64, 1024);
        // dt_proj: (T,32 of 64) x (1024,32)^T + dt_b, softplus -> dtf (T,1024)
        gemm_bt<1><<<dim3(32, 16), 256, 0, stream>>>(
            dbc, 64, dtw, (long)l * 1024 * 32, dtf, dtb, (long)l * 1024,
            flag, 1024, 32);
        scan_stage1<<<256, 256, 0, stream>>>(dtf, xi, dbc, alog, (long)l * 16384,
                                             flag, P, S);
        scan_stage2<<<128, 256, 0, stream>>>(P, S);
        scan_stage3<<<256, 256, 0, stream>>>(dtf, xi, dbc, alog, (long)l * 16384,
                                             Dw, (long)l * 1024, flag, xz, P);
        // out_proj: (T,1024) x (512,1024)^T -> h (T,512); last layer -> d_out
        float* outp = (l < 5) ? h : (float*)d_out;
        gemm_bt<0><<<dim3(32, 8), 256, 0, stream>>>(
            xi, 1024, ow, (long)l * 512 * 1024, outp, nullptr, 0, flag, 512, 1024);
    }
}

// Round 5
// 1104.388 us; speedup vs baseline: 1.4452x; 1.0773x over previous
//
#include <hip/hip_runtime.h>
#include <hip/hip_bf16.h>

// ---------------------------------------------------------------------------
// Mamba encoder fwd: B=2, L=1024, D=512, E=1024, N=16, R=32, 6 layers.
// Inputs fp32 (probe-confirmed; dynamic probe kept). Output fp32.
// GEMMs: split-bf16 (hi/lo, 3 MFMAs) with ALL splitting hoisted out of the
// K-loop: weights pre-split once per launch, activations emitted pre-split.
// Scan: chunked (32 x 32), lane axis = e, 16 states in registers.
// ws_size = 256 MiB (fill-evidence); we use ~107 MB.
// ---------------------------------------------------------------------------

typedef __attribute__((ext_vector_type(8))) short bf16x8;
typedef __attribute__((ext_vector_type(4))) float f32x4;

__device__ __forceinline__ float bf2f(unsigned short u) {
    unsigned int x = ((unsigned int)u) << 16;
    return __builtin_bit_cast(float, x);
}
__device__ __forceinline__ unsigned short f2bf(float f) {
    __hip_bfloat16 h = __float2bfloat16(f);   // RNE
    return __builtin_bit_cast(unsigned short, h);
}
__device__ __forceinline__ float ldin(const void* p, size_t i, int isbf) {
    return isbf ? bf2f(((const unsigned short*)p)[i]) : ((const float*)p)[i];
}
__device__ __forceinline__ float softplus_f(float x) {
    return (x > 20.f) ? x : log1pf(__expf(x));
}
__device__ __forceinline__ void split2(float x, unsigned short& h, unsigned short& l) {
    h = f2bf(x);
    l = f2bf(x - bf2f(h));
}

// ------------------------- dtype probe (D == 1.0) ---------------------------
__global__ void dtype_probe(const void* __restrict__ D, int* __restrict__ flag) {
    *flag = (*(const unsigned int*)D == 0x3F800000u) ? 0 : 1;
}

// ------------------------- x -> fp32 h (layer 0) ----------------------------
__global__ __launch_bounds__(256) void cvt_in(const void* __restrict__ x,
                                              const int* __restrict__ flag,
                                              float* __restrict__ h, int n) {
    const int isbf = *flag;
    int g = blockIdx.x * 256 + threadIdx.x;
    if (g < n) h[g] = ldin(x, g, isbf);
}

// ---------------- weight pre-split: fp32/bf16 -> bf16 hi + lo ---------------
__global__ __launch_bounds__(256) void wconv(const void* __restrict__ W,
                                             const int* __restrict__ flag,
                                             unsigned short* __restrict__ Wh,
                                             unsigned short* __restrict__ Wl, int n) {
    const int isbf = *flag;
    int g = blockIdx.x * 256 + threadIdx.x;
    if (g >= n) return;
    if (isbf) { Wh[g] = ((const unsigned short*)W)[g]; Wl[g] = 0; }
    else {
        unsigned short hh, ll;
        split2(((const float*)W)[g], hh, ll);
        Wh[g] = hh; Wl[g] = ll;
    }
}

// --------------------------- GEMM: C = A * W^T ------------------------------
// A: M x K bf16 hi/lo (pre-split), row stride lda.  W: N x K bf16 hi/lo.
// Optional split-K via blockIdx.z (chunk Kc, output offset z*zstride).
// acc += Ah*Wh + Ah*Wl + Al*Wh.  Tile 64x64, BK=32, 256 threads.
template <int ACT>
__global__ __launch_bounds__(256) void gemm_hl(
    const unsigned short* __restrict__ Ah, const unsigned short* __restrict__ Al,
    int lda,
    const unsigned short* __restrict__ Wh, const unsigned short* __restrict__ Wl,
    long woff,
    float* __restrict__ Cf, long zstride,
    const void* __restrict__ bias, long boff, const int* __restrict__ flag,
    int N, int K, int Kc)
{
    const int isbf = *flag;
    __shared__ __align__(16) unsigned short As[2][64][40];   // 80B row: 16-al
    __shared__ __align__(16) unsigned short Ws[2][64][40];

    const int m0 = blockIdx.x * 64, n0 = blockIdx.y * 64;
    const int kb = blockIdx.z * Kc;
    const int t = threadIdx.x;
    const int lane = t & 63, wave = t >> 6;
    const int wm = (wave & 1) * 32, wn = (wave >> 1) * 32;
    const int srow = t >> 2, scol = (t & 3) * 8;

    const unsigned short* ah = Ah + (size_t)(m0 + srow) * lda + scol;
    const unsigned short* al = Al + (size_t)(m0 + srow) * lda + scol;
    const unsigned short* wh = Wh + woff + (size_t)(n0 + srow) * K + scol;
    const unsigned short* wl = Wl + woff + (size_t)(n0 + srow) * K + scol;

    f32x4 acc[2][2] = {};

    for (int k0 = kb; k0 < kb + Kc; k0 += 32) {
        __syncthreads();
        *(uint4*)(&As[0][srow][scol]) = *(const uint4*)(ah + k0);
        *(uint4*)(&As[1][srow][scol]) = *(const uint4*)(al + k0);
        *(uint4*)(&Ws[0][srow][scol]) = *(const uint4*)(wh + k0);
        *(uint4*)(&Ws[1][srow][scol]) = *(const uint4*)(wl + k0);
        __syncthreads();

        const int fm = lane & 15, fk = (lane >> 4) * 8;
        bf16x8 a0h = *(const bf16x8*)(&As[0][wm + fm][fk]);
        bf16x8 a1h = *(const bf16x8*)(&As[0][wm + 16 + fm][fk]);
        bf16x8 w0h = *(const bf16x8*)(&Ws[0][wn + fm][fk]);
        bf16x8 w1h = *(const bf16x8*)(&Ws[0][wn + 16 + fm][fk]);
        bf16x8 a0l = *(const bf16x8*)(&As[1][wm + fm][fk]);
        bf16x8 a1l = *(const bf16x8*)(&As[1][wm + 16 + fm][fk]);
        bf16x8 w0l = *(const bf16x8*)(&Ws[1][wn + fm][fk]);
        bf16x8 w1l = *(const bf16x8*)(&Ws[1][wn + 16 + fm][fk]);

        acc[0][0] = __builtin_amdgcn_mfma_f32_16x16x32_bf16(a0h, w0h, acc[0][0], 0, 0, 0);
        acc[0][1] = __builtin_amdgcn_mfma_f32_16x16x32_bf16(a0h, w1h, acc[0][1], 0, 0, 0);
        acc[1][0] = __builtin_amdgcn_mfma_f32_16x16x32_bf16(a1h, w0h, acc[1][0], 0, 0, 0);
        acc[1][1] = __builtin_amdgcn_mfma_f32_16x16x32_bf16(a1h, w1h, acc[1][1], 0, 0, 0);
        acc[0][0] = __builtin_amdgcn_mfma_f32_16x16x32_bf16(a0h, w0l, acc[0][0], 0, 0, 0);
        acc[0][1] = __builtin_amdgcn_mfma_f32_16x16x32_bf16(a0h, w1l, acc[0][1], 0, 0, 0);
        acc[1][0] = __builtin_amdgcn_mfma_f32_16x16x32_bf16(a1h, w0l, acc[1][0], 0, 0, 0);
        acc[1][1] = __builtin_amdgcn_mfma_f32_16x16x32_bf16(a1h, w1l, acc[1][1], 0, 0, 0);
        acc[0][0] = __builtin_amdgcn_mfma_f32_16x16x32_bf16(a0l, w0h, acc[0][0], 0, 0, 0);
        acc[0][1] = __builtin_amdgcn_mfma_f32_16x16x32_bf16(a0l, w1h, acc[0][1], 0, 0, 0);
        acc[1][0] = __builtin_amdgcn_mfma_f32_16x16x32_bf16(a1l, w0h, acc[1][0], 0, 0, 0);
        acc[1][1] = __builtin_amdgcn_mfma_f32_16x16x32_bf16(a1l, w1h, acc[1][1], 0, 0, 0);
    }

    float* Cp = Cf + (size_t)blockIdx.z * zstride;
    const int col = lane & 15, rb = (lane >> 4) * 4;
#pragma unroll
    for (int mi = 0; mi < 2; ++mi)
#pragma unroll
        for (int ni = 0; ni < 2; ++ni)
#pragma unroll
            for (int r = 0; r < 4; ++r) {
                int gm = m0 + wm + mi * 16 + rb + r;
                int gn = n0 + wn + ni * 16 + col;
                float v = acc[mi][ni][r];
                if (bias) v += ldin(bias, boff + gn, isbf);
                if (ACT == 1) v = softplus_f(v);
                Cp[(size_t)gm * N + gn] = v;
            }
}

// ------------- split-K reduce for x_proj + dt-operand pre-split -------------
__global__ __launch_bounds__(256) void xp_reduce(
    const float* __restrict__ Pxp, float* __restrict__ dbc,
    unsigned short* __restrict__ dth, unsigned short* __restrict__ dtl)
{
    int g = blockIdx.x * 256 + threadIdx.x;   // 131072 = 2048*64
    float s = 0.f;
#pragma unroll
    for (int z = 0; z < 8; ++z) s += Pxp[(size_t)z * 131072 + g];
    dbc[g] = s;
    int n = g & 63, t = g >> 6;
    if (n < 32) {
        unsigned short hh, ll;
        split2(s, hh, ll);
        dth[t * 32 + n] = hh; dtl[t * 32 + n] = ll;
    }
}

// ------------------- RMSNorm(h + pos) -> pre-split bf16 ---------------------
__global__ __launch_bounds__(256) void rmsnorm_k(
    const float* __restrict__ h, const void* __restrict__ pos,
    const void* __restrict__ nw, const int* __restrict__ flag,
    unsigned short* __restrict__ xnh, unsigned short* __restrict__ xnl)
{
    const int isbf = *flag;
    const int row = blockIdx.x;
    const int t = threadIdx.x;
    const size_t base = (size_t)row * 512;
    float v0 = h[base + t]       + ldin(pos, base + t, isbf);
    float v1 = h[base + 256 + t] + ldin(pos, base + 256 + t, isbf);
    float ss = v0 * v0 + v1 * v1;
#pragma unroll
    for (int o = 32; o; o >>= 1) ss += __shfl_xor(ss, o, 64);
    __shared__ float sw[4];
    if ((t & 63) == 0) sw[t >> 6] = ss;
    __syncthreads();
    float tot = sw[0] + sw[1] + sw[2] + sw[3];
    float sc = rsqrtf(tot * (1.0f / 512.0f) + 1.1920929e-07f);
    float o0 = v0 * sc * ldin(nw, t, isbf);
    float o1 = v1 * sc * ldin(nw, 256 + t, isbf);
    unsigned short hh, ll;
    split2(o0, hh, ll); xnh[base + t] = hh;       xnl[base + t] = ll;
    split2(o1, hh, ll); xnh[base + 256 + t] = hh; xnl[base + 256 + t] = ll;
}

// ------- causal depthwise conv (k=4) + SiLU -> fp32 u + pre-split bf16 ------
__global__ __launch_bounds__(256) void conv_silu_k(
    const float* __restrict__ xz,
    const void* __restrict__ cw, long cwoff,
    const void* __restrict__ cb, long cboff,
    const int* __restrict__ flag,
    float* __restrict__ xi,
    unsigned short* __restrict__ xih, unsigned short* __restrict__ xil)
{
    const int isbf = *flag;
    int g = blockIdx.x * 256 + threadIdx.x;   // T*E = 2M
    int e = g & 1023;
    int l = (g >> 10) & 1023;
    int b = g >> 20;
    float acc = ldin(cb, cboff + e, isbf);
#pragma unroll
    for (int k = 0; k < 4; ++k) {
        int ls = l - 3 + k;
        if (ls >= 0)
            acc += ldin(cw, cwoff + e * 4 + k, isbf) *
                   xz[((size_t)(b * 1024 + ls)) * 2048 + e];
    }
    acc = acc / (1.f + __expf(-acc));         // SiLU
    xi[g] = acc;
    unsigned short hh, ll;
    split2(acc, hh, ll);
    xih[g] = hh; xil[g] = ll;
}

// --------------------- selective scan, chunked (32 x 32) --------------------
// Thread = (b, c, e); lane axis = e; 16 states in registers.
// P,S,H0 layout: [b][c][n][e].

__global__ __launch_bounds__(256) void scan_stage1(
    const float* __restrict__ dtp, const float* __restrict__ u,
    const float* __restrict__ dbc,
    const void* __restrict__ alog, long aoff, const int* __restrict__ flag,
    float* __restrict__ P, float* __restrict__ S)
{
    const int isbf = *flag;
    int g = blockIdx.x * 256 + threadIdx.x;   // 65536
    int e = g & 1023, c = (g >> 10) & 31, b = g >> 15;

    float Aen[16], Pn[16], Sn[16];
#pragma unroll
    for (int n = 0; n < 16; ++n) {
        Aen[n] = -__expf(ldin(alog, aoff + e * 16 + n, isbf));
        Pn[n] = 1.f; Sn[n] = 0.f;
    }
    int t0 = b * 1024 + c * 32;
    for (int i = 0; i < 32; ++i) {
        int t = t0 + i;
        float d  = dtp[(size_t)t * 1024 + e];
        float du = d * u[(size_t)t * 1024 + e];
        const float4* Bp = (const float4*)(dbc + (size_t)t * 64 + 32);
        float4 b0 = Bp[0], b1 = Bp[1], b2 = Bp[2], b3 = Bp[3];
        float Bt[16] = {b0.x,b0.y,b0.z,b0.w, b1.x,b1.y,b1.z,b1.w,
                        b2.x,b2.y,b2.z,b2.w, b3.x,b3.y,b3.z,b3.w};
#pragma unroll
        for (int n = 0; n < 16; ++n) {
            float a = __expf(d * Aen[n]);
            Sn[n] = a * Sn[n] + du * Bt[n];
            Pn[n] *= a;
        }
    }
    size_t ob = ((size_t)(b * 32 + c) * 16) * 1024 + e;
#pragma unroll
    for (int n = 0; n < 16; ++n) {
        P[ob + (size_t)n * 1024] = Pn[n];
        S[ob + (size_t)n * 1024] = Sn[n];
    }
}

__global__ __launch_bounds__(256) void scan_stage2(
    float* __restrict__ PH, const float* __restrict__ S)
{
    int g = blockIdx.x * 256 + threadIdx.x;   // 32768: e + 1024n + 16384b
    int e = g & 1023, n = (g >> 10) & 15, b = g >> 14;
    float H = 0.f;
#pragma unroll
    for (int c = 0; c < 32; ++c) {
        size_t idx = ((size_t)(b * 32 + c) * 16 + n) * 1024 + e;
        float p = PH[idx], s = S[idx];
        PH[idx] = H;
        H = p * H + s;
    }
}

// final sweep: y = sum_n C*h + u*D, gate with silu(z); emit pre-split bf16.
__global__ __launch_bounds__(256) void scan_stage3(
    const float* __restrict__ dtp, const float* __restrict__ u,
    const float* __restrict__ dbc,
    const void* __restrict__ alog, long aoff,
    const void* __restrict__ Dv, long doff,
    const int* __restrict__ flag,
    const float* __restrict__ xz, const float* __restrict__ H0,
    unsigned short* __restrict__ yh, unsigned short* __restrict__ yl)
{
    const int isbf = *flag;
    int g = blockIdx.x * 256 + threadIdx.x;   // 65536
    int e = g & 1023, c = (g >> 10) & 31, b = g >> 15;

    float Aen[16], h[16];
    size_t ob = ((size_t)(b * 32 + c) * 16) * 1024 + e;
#pragma unroll
    for (int n = 0; n < 16; ++n) {
        Aen[n] = -__expf(ldin(alog, aoff + e * 16 + n, isbf));
        h[n] = H0[ob + (size_t)n * 1024];
    }
    float De = ldin(Dv, doff + e, isbf);
    int t0 = b * 1024 + c * 32;
    for (int i = 0; i < 32; ++i) {
        int t = t0 + i;
        float d  = dtp[(size_t)t * 1024 + e];
        float uu = u[(size_t)t * 1024 + e];
        float du = d * uu;
        const float4* Bp = (const float4*)(dbc + (size_t)t * 64 + 32);
        float4 b0 = Bp[0], b1 = Bp[1], b2 = Bp[2], b3 = Bp[3];
        float4 c0 = Bp[4], c1 = Bp[5], c2 = Bp[6], c3 = Bp[7];
        float Bt[16] = {b0.x,b0.y,b0.z,b0.w, b1.x,b1.y,b1.z,b1.w,
                        b2.x,b2.y,b2.z,b2.w, b3.x,b3.y,b3.z,b3.w};
        float Ct[16] = {c0.x,c0.y,c0.z,c0.w, c1.x,c1.y,c1.z,c1.w,
                        c2.x,c2.y,c2.z,c2.w, c3.x,c3.y,c3.z,c3.w};
        float y = 0.f;
#pragma unroll
        for (int n = 0; n < 16; ++n) {
            float a = __expf(d * Aen[n]);
            h[n] = a * h[n] + du * Bt[n];
            y += h[n] * Ct[n];
        }
        float z = xz[(size_t)t * 2048 + 1024 + e];
        float sz = z / (1.f + __expf(-z));
        float yv = (y + uu * De) * sz;
        unsigned short hh, ll;
        split2(yv, hh, ll);
        yh[(size_t)t * 1024 + e] = hh;
        yl[(size_t)t * 1024 + e] = ll;
    }
}

// ------------------------------- launcher -----------------------------------
extern "C" void kernel_launch(void* const* d_in, const int* in_sizes, int n_in,
                              void* d_out, int out_size, void* d_ws, size_t ws_size,
                              hipStream_t stream)
{
    const void* x    = d_in[0];
    const void* pos  = d_in[1];
    const void* nw   = d_in[2];
    const void* ipw  = d_in[3];   // (6,2048,512)
    const void* cw   = d_in[4];   // (6,1024,4)
    const void* cb   = d_in[5];   // (6,1024)
    const void* xpw  = d_in[6];   // (6,64,1024)
    const void* dtw  = d_in[7];   // (6,1024,32)
    const void* dtb  = d_in[8];   // (6,1024)
    const void* alog = d_in[9];   // (6,1024,16)
    const void* Dw   = d_in[10];  // (6,1024)
    const void* ow   = d_in[11];  // (6,512,1024)

    char* w = (char*)d_ws;
    auto take = [&](size_t bytes) { char* p = w; w += (bytes + 255) & ~255ull; return p; };

    float* h    = (float*)take(2048ull * 512 * 4);          // 4 MB
    float* xz   = (float*)take(2048ull * 2048 * 4);         // 16 MB
    float* xi   = (float*)take(2048ull * 1024 * 4);         // 8 MB
    float* dtf  = (float*)take(2048ull * 1024 * 4);         // 8 MB
    float* dbc  = (float*)take(2048ull * 64 * 4);           // 0.5 MB
    float* P    = (float*)take(2ull * 32 * 16 * 1024 * 4);  // 4 MB (also H0)
    float* S    = (float*)take(2ull * 32 * 16 * 1024 * 4);  // 4 MB
    float* Pxp  = (float*)take(8ull * 2048 * 64 * 4);       // 4 MB
    unsigned short* xnh = (unsigned short*)take(2048ull * 512 * 2);
    unsigned short* xnl = (unsigned short*)take(2048ull * 512 * 2);
    unsigned short* xih = (unsigned short*)take(2048ull * 1024 * 2);
    unsigned short* xil = (unsigned short*)take(2048ull * 1024 * 2);
    unsigned short* yh  = (unsigned short*)take(2048ull * 1024 * 2);
    unsigned short* yl  = (unsigned short*)take(2048ull * 1024 * 2);
    unsigned short* dth = (unsigned short*)take(2048ull * 32 * 2);
    unsigned short* dtl = (unsigned short*)take(2048ull * 32 * 2);
    unsigned short* wip_h = (unsigned short*)take(6ull * 2048 * 512 * 2);
    unsigned short* wip_l = (unsigned short*)take(6ull * 2048 * 512 * 2);
    unsigned short* wow_h = (unsigned short*)take(6ull * 512 * 1024 * 2);
    unsigned short* wow_l = (unsigned short*)take(6ull * 512 * 1024 * 2);
    unsigned short* wxp_h = (unsigned short*)take(6ull * 64 * 1024 * 2);
    unsigned short* wxp_l = (unsigned short*)take(6ull * 64 * 1024 * 2);
    unsigned short* wdt_h = (unsigned short*)take(6ull * 1024 * 32 * 2);
    unsigned short* wdt_l = (unsigned short*)take(6ull * 1024 * 32 * 2);
    int* flag = (int*)take(256);                            // total ~107 MB

    dtype_probe<<<1, 1, 0, stream>>>(Dw, flag);
    cvt_in<<<4096, 256, 0, stream>>>(x, flag, h, 2048 * 512);
    wconv<<<24576, 256, 0, stream>>>(ipw, flag, wip_h, wip_l, 6 * 2048 * 512);
    wconv<<<12288, 256, 0, stream>>>(ow,  flag, wow_h, wow_l, 6 * 512 * 1024);
    wconv<<<1536, 256, 0, stream>>>(xpw, flag, wxp_h, wxp_l, 6 * 64 * 1024);
    wconv<<<768,  256, 0, stream>>>(dtw, flag, wdt_h, wdt_l, 6 * 1024 * 32);

    for (int l = 0; l < 6; ++l) {
        rmsnorm_k<<<2048, 256, 0, stream>>>(h, pos, nw, flag, xnh, xnl);
        // in_proj: (T,512) x (2048,512)^T -> xz (T,2048)
        gemm_hl<0><<<dim3(32, 32), 256, 0, stream>>>(
            xnh, xnl, 512, wip_h, wip_l, (long)l * 2048 * 512,
            xz, 0, nullptr, 0, flag, 2048, 512, 512);
        conv_silu_k<<<8192, 256, 0, stream>>>(xz, cw, (long)l * 4096, cb, (long)l * 1024,
                                              flag, xi, xih, xil);
        // x_proj: (T,1024) x (64,1024)^T, split-K x8 -> Pxp, then reduce
        gemm_hl<0><<<dim3(32, 1, 8), 256, 0, stream>>>(
            xih, xil, 1024, wxp_h, wxp_l, (long)l * 64 * 1024,
            Pxp, 2048l * 64, nullptr, 0, flag, 64, 1024, 128);
        xp_reduce<<<512, 256, 0, stream>>>(Pxp, dbc, dth, dtl);
        // dt_proj: (T,32) x (1024,32)^T + dt_b, softplus -> dtf (T,1024)
        gemm_hl<1><<<dim3(32, 16), 256, 0, stream>>>(
            dth, dtl, 32, wdt_h, wdt_l, (long)l * 1024 * 32,
            dtf, 0, dtb, (long)l * 1024, flag, 1024, 32, 32);
        scan_stage1<<<256, 256, 0, stream>>>(dtf, xi, dbc, alog, (long)l * 16384,
                                             flag, P, S);
        scan_stage2<<<128, 256, 0, stream>>>(P, S);
        scan_stage3<<<256, 256, 0, stream>>>(dtf, xi, dbc, alog, (long)l * 16384,
                                             Dw, (long)l * 1024, flag, xz, P, yh, yl);
        // out_proj: (T,1024) x (512,1024)^T -> h (T,512); last layer -> d_out
        float* outp = (l < 5) ? h : (float*)d_out;
        gemm_hl<0><<<dim3(32, 8), 256, 0, stream>>>(
            yh, yl, 1024, wow_h, wow_l, (long)l * 512 * 1024,
            outp, 0, nullptr, 0, flag, 512, 1024, 1024);
    }
}

// Round 6
// 877.777 us; speedup vs baseline: 1.8183x; 1.2582x over previous
//
#include <hip/hip_runtime.h>
#include <hip/hip_bf16.h>

// ---------------------------------------------------------------------------
// Mamba encoder fwd: B=2, L=1024, D=512, E=1024, N=16, R=32, 6 layers.
// Inputs fp32 (probe-confirmed; dynamic probe kept). Output fp32.
// GEMMs: split-bf16 (hi/lo, 3 MFMAs), weights pre-split once, activations
// emitted pre-split by producers.
// Scan: chunked 64 x 16, lane axis = e, chunk operands batch-preloaded into
// registers, fully unrolled recurrence (latency-hiding by ILP, not TLP).
// ws_size = 256 MiB (fill-evidence); we use ~115 MB.
// ---------------------------------------------------------------------------

typedef __attribute__((ext_vector_type(8))) short bf16x8;
typedef __attribute__((ext_vector_type(4))) float f32x4;

__device__ __forceinline__ float bf2f(unsigned short u) {
    unsigned int x = ((unsigned int)u) << 16;
    return __builtin_bit_cast(float, x);
}
__device__ __forceinline__ unsigned short f2bf(float f) {
    __hip_bfloat16 h = __float2bfloat16(f);   // RNE
    return __builtin_bit_cast(unsigned short, h);
}
__device__ __forceinline__ float ldin(const void* p, size_t i, int isbf) {
    return isbf ? bf2f(((const unsigned short*)p)[i]) : ((const float*)p)[i];
}
__device__ __forceinline__ float softplus_f(float x) {
    return (x > 20.f) ? x : log1pf(__expf(x));
}
__device__ __forceinline__ void split2(float x, unsigned short& h, unsigned short& l) {
    h = f2bf(x);
    l = f2bf(x - bf2f(h));
}

// ------------------------- dtype probe (D == 1.0) ---------------------------
__global__ void dtype_probe(const void* __restrict__ D, int* __restrict__ flag) {
    *flag = (*(const unsigned int*)D == 0x3F800000u) ? 0 : 1;
}

// ------------------------- x -> fp32 h (layer 0) ----------------------------
__global__ __launch_bounds__(256) void cvt_in(const void* __restrict__ x,
                                              const int* __restrict__ flag,
                                              float* __restrict__ h, int n) {
    const int isbf = *flag;
    int g = blockIdx.x * 256 + threadIdx.x;
    if (g < n) h[g] = ldin(x, g, isbf);
}

// ---------------- weight pre-split: fp32/bf16 -> bf16 hi + lo ---------------
__global__ __launch_bounds__(256) void wconv(const void* __restrict__ W,
                                             const int* __restrict__ flag,
                                             unsigned short* __restrict__ Wh,
                                             unsigned short* __restrict__ Wl, int n) {
    const int isbf = *flag;
    int g = blockIdx.x * 256 + threadIdx.x;
    if (g >= n) return;
    if (isbf) { Wh[g] = ((const unsigned short*)W)[g]; Wl[g] = 0; }
    else {
        unsigned short hh, ll;
        split2(((const float*)W)[g], hh, ll);
        Wh[g] = hh; Wl[g] = ll;
    }
}

// --------------------------- GEMM: C = A * W^T ------------------------------
// A: M x K bf16 hi/lo (pre-split), row stride lda.  W: N x K bf16 hi/lo.
// Optional split-K via blockIdx.z.  acc += Ah*Wh + Ah*Wl + Al*Wh.
template <int ACT>
__global__ __launch_bounds__(256) void gemm_hl(
    const unsigned short* __restrict__ Ah, const unsigned short* __restrict__ Al,
    int lda,
    const unsigned short* __restrict__ Wh, const unsigned short* __restrict__ Wl,
    long woff,
    float* __restrict__ Cf, long zstride,
    const void* __restrict__ bias, long boff, const int* __restrict__ flag,
    int N, int K, int Kc)
{
    const int isbf = *flag;
    __shared__ __align__(16) unsigned short As[2][64][40];
    __shared__ __align__(16) unsigned short Ws[2][64][40];

    const int m0 = blockIdx.x * 64, n0 = blockIdx.y * 64;
    const int kb = blockIdx.z * Kc;
    const int t = threadIdx.x;
    const int lane = t & 63, wave = t >> 6;
    const int wm = (wave & 1) * 32, wn = (wave >> 1) * 32;
    const int srow = t >> 2, scol = (t & 3) * 8;

    const unsigned short* ah = Ah + (size_t)(m0 + srow) * lda + scol;
    const unsigned short* al = Al + (size_t)(m0 + srow) * lda + scol;
    const unsigned short* wh = Wh + woff + (size_t)(n0 + srow) * K + scol;
    const unsigned short* wl = Wl + woff + (size_t)(n0 + srow) * K + scol;

    f32x4 acc[2][2] = {};

    for (int k0 = kb; k0 < kb + Kc; k0 += 32) {
        __syncthreads();
        *(uint4*)(&As[0][srow][scol]) = *(const uint4*)(ah + k0);
        *(uint4*)(&As[1][srow][scol]) = *(const uint4*)(al + k0);
        *(uint4*)(&Ws[0][srow][scol]) = *(const uint4*)(wh + k0);
        *(uint4*)(&Ws[1][srow][scol]) = *(const uint4*)(wl + k0);
        __syncthreads();

        const int fm = lane & 15, fk = (lane >> 4) * 8;
        bf16x8 a0h = *(const bf16x8*)(&As[0][wm + fm][fk]);
        bf16x8 a1h = *(const bf16x8*)(&As[0][wm + 16 + fm][fk]);
        bf16x8 w0h = *(const bf16x8*)(&Ws[0][wn + fm][fk]);
        bf16x8 w1h = *(const bf16x8*)(&Ws[0][wn + 16 + fm][fk]);
        bf16x8 a0l = *(const bf16x8*)(&As[1][wm + fm][fk]);
        bf16x8 a1l = *(const bf16x8*)(&As[1][wm + 16 + fm][fk]);
        bf16x8 w0l = *(const bf16x8*)(&Ws[1][wn + fm][fk]);
        bf16x8 w1l = *(const bf16x8*)(&Ws[1][wn + 16 + fm][fk]);

        acc[0][0] = __builtin_amdgcn_mfma_f32_16x16x32_bf16(a0h, w0h, acc[0][0], 0, 0, 0);
        acc[0][1] = __builtin_amdgcn_mfma_f32_16x16x32_bf16(a0h, w1h, acc[0][1], 0, 0, 0);
        acc[1][0] = __builtin_amdgcn_mfma_f32_16x16x32_bf16(a1h, w0h, acc[1][0], 0, 0, 0);
        acc[1][1] = __builtin_amdgcn_mfma_f32_16x16x32_bf16(a1h, w1h, acc[1][1], 0, 0, 0);
        acc[0][0] = __builtin_amdgcn_mfma_f32_16x16x32_bf16(a0h, w0l, acc[0][0], 0, 0, 0);
        acc[0][1] = __builtin_amdgcn_mfma_f32_16x16x32_bf16(a0h, w1l, acc[0][1], 0, 0, 0);
        acc[1][0] = __builtin_amdgcn_mfma_f32_16x16x32_bf16(a1h, w0l, acc[1][0], 0, 0, 0);
        acc[1][1] = __builtin_amdgcn_mfma_f32_16x16x32_bf16(a1h, w1l, acc[1][1], 0, 0, 0);
        acc[0][0] = __builtin_amdgcn_mfma_f32_16x16x32_bf16(a0l, w0h, acc[0][0], 0, 0, 0);
        acc[0][1] = __builtin_amdgcn_mfma_f32_16x16x32_bf16(a0l, w1h, acc[0][1], 0, 0, 0);
        acc[1][0] = __builtin_amdgcn_mfma_f32_16x16x32_bf16(a1l, w0h, acc[1][0], 0, 0, 0);
        acc[1][1] = __builtin_amdgcn_mfma_f32_16x16x32_bf16(a1l, w1h, acc[1][1], 0, 0, 0);
    }

    float* Cp = Cf + (size_t)blockIdx.z * zstride;
    const int col = lane & 15, rb = (lane >> 4) * 4;
#pragma unroll
    for (int mi = 0; mi < 2; ++mi)
#pragma unroll
        for (int ni = 0; ni < 2; ++ni)
#pragma unroll
            for (int r = 0; r < 4; ++r) {
                int gm = m0 + wm + mi * 16 + rb + r;
                int gn = n0 + wn + ni * 16 + col;
                float v = acc[mi][ni][r];
                if (bias) v += ldin(bias, boff + gn, isbf);
                if (ACT == 1) v = softplus_f(v);
                Cp[(size_t)gm * N + gn] = v;
            }
}

// ------------- split-K reduce for x_proj + dt-operand pre-split -------------
__global__ __launch_bounds__(256) void xp_reduce(
    const float* __restrict__ Pxp, float* __restrict__ dbc,
    unsigned short* __restrict__ dth, unsigned short* __restrict__ dtl)
{
    int g = blockIdx.x * 256 + threadIdx.x;   // 131072 = 2048*64
    float s = 0.f;
#pragma unroll
    for (int z = 0; z < 8; ++z) s += Pxp[(size_t)z * 131072 + g];
    dbc[g] = s;
    int n = g & 63, t = g >> 6;
    if (n < 32) {
        unsigned short hh, ll;
        split2(s, hh, ll);
        dth[t * 32 + n] = hh; dtl[t * 32 + n] = ll;
    }
}

// ------------------- RMSNorm(h + pos) -> pre-split bf16 ---------------------
__global__ __launch_bounds__(256) void rmsnorm_k(
    const float* __restrict__ h, const void* __restrict__ pos,
    const void* __restrict__ nw, const int* __restrict__ flag,
    unsigned short* __restrict__ xnh, unsigned short* __restrict__ xnl)
{
    const int isbf = *flag;
    const int row = blockIdx.x;
    const int t = threadIdx.x;
    const size_t base = (size_t)row * 512;
    float v0 = h[base + t]       + ldin(pos, base + t, isbf);
    float v1 = h[base + 256 + t] + ldin(pos, base + 256 + t, isbf);
    float ss = v0 * v0 + v1 * v1;
#pragma unroll
    for (int o = 32; o; o >>= 1) ss += __shfl_xor(ss, o, 64);
    __shared__ float sw[4];
    if ((t & 63) == 0) sw[t >> 6] = ss;
    __syncthreads();
    float tot = sw[0] + sw[1] + sw[2] + sw[3];
    float sc = rsqrtf(tot * (1.0f / 512.0f) + 1.1920929e-07f);
    float o0 = v0 * sc * ldin(nw, t, isbf);
    float o1 = v1 * sc * ldin(nw, 256 + t, isbf);
    unsigned short hh, ll;
    split2(o0, hh, ll); xnh[base + t] = hh;       xnl[base + t] = ll;
    split2(o1, hh, ll); xnh[base + 256 + t] = hh; xnl[base + 256 + t] = ll;
}

// ------- causal depthwise conv (k=4) + SiLU -> fp32 u + pre-split bf16 ------
__global__ __launch_bounds__(256) void conv_silu_k(
    const float* __restrict__ xz,
    const void* __restrict__ cw, long cwoff,
    const void* __restrict__ cb, long cboff,
    const int* __restrict__ flag,
    float* __restrict__ xi,
    unsigned short* __restrict__ xih, unsigned short* __restrict__ xil)
{
    const int isbf = *flag;
    int g = blockIdx.x * 256 + threadIdx.x;   // T*E = 2M
    int e = g & 1023;
    int l = (g >> 10) & 1023;
    int b = g >> 20;
    float acc = ldin(cb, cboff + e, isbf);
#pragma unroll
    for (int k = 0; k < 4; ++k) {
        int ls = l - 3 + k;
        if (ls >= 0)
            acc += ldin(cw, cwoff + e * 4 + k, isbf) *
                   xz[((size_t)(b * 1024 + ls)) * 2048 + e];
    }
    acc = acc / (1.f + __expf(-acc));         // SiLU
    xi[g] = acc;
    unsigned short hh, ll;
    split2(acc, hh, ll);
    xih[g] = hh; xil[g] = ll;
}

// --------------------- selective scan, chunked (64 x 16) --------------------
// Thread = (b, c, e); lane axis = e; 16 states in registers.
// Chunk operands (dt, u, z) batch-preloaded into registers, loop fully
// unrolled -> no load latency inside the recurrence chain.
// P,S,H0 layout: [b][c][n][e] -> ((b*64+c)*16+n)*1024 + e.

#define CL 16
#define NCH 64

__global__ __launch_bounds__(256) void scan_stage1(
    const float* __restrict__ dtp, const float* __restrict__ u,
    const float* __restrict__ dbc,
    const void* __restrict__ alog, long aoff, const int* __restrict__ flag,
    float* __restrict__ P, float* __restrict__ S)
{
    const int isbf = *flag;
    int g = blockIdx.x * 256 + threadIdx.x;   // 131072
    int e = g & 1023, c = (g >> 10) & (NCH - 1), b = g >> 16;
    int t0 = b * 1024 + c * CL;

    float dv[CL], uv[CL];
#pragma unroll
    for (int i = 0; i < CL; ++i) {
        dv[i] = dtp[(size_t)(t0 + i) * 1024 + e];
        uv[i] = u[(size_t)(t0 + i) * 1024 + e];
    }

    float Aen[16], Pn[16], Sn[16];
#pragma unroll
    for (int n = 0; n < 16; ++n) {
        Aen[n] = -__expf(ldin(alog, aoff + e * 16 + n, isbf));
        Pn[n] = 1.f; Sn[n] = 0.f;
    }
#pragma unroll
    for (int i = 0; i < CL; ++i) {
        float d = dv[i], du = d * uv[i];
        const float4* Bp = (const float4*)(dbc + (size_t)(t0 + i) * 64 + 32);
        float4 b0 = Bp[0], b1 = Bp[1], b2 = Bp[2], b3 = Bp[3];
        float Bt[16] = {b0.x,b0.y,b0.z,b0.w, b1.x,b1.y,b1.z,b1.w,
                        b2.x,b2.y,b2.z,b2.w, b3.x,b3.y,b3.z,b3.w};
#pragma unroll
        for (int n = 0; n < 16; ++n) {
            float a = __expf(d * Aen[n]);
            Sn[n] = a * Sn[n] + du * Bt[n];
            Pn[n] *= a;
        }
    }
    size_t ob = ((size_t)(b * NCH + c) * 16) * 1024 + e;
#pragma unroll
    for (int n = 0; n < 16; ++n) {
        P[ob + (size_t)n * 1024] = Pn[n];
        S[ob + (size_t)n * 1024] = Sn[n];
    }
}

// cross-chunk combine IN PLACE: PH holds P on entry, H0 on exit.
__global__ __launch_bounds__(256) void scan_stage2(
    float* __restrict__ PH, const float* __restrict__ S)
{
    int g = blockIdx.x * 256 + threadIdx.x;   // 32768: e + 1024n + 16384b
    int e = g & 1023, n = (g >> 10) & 15, b = g >> 14;
    float H = 0.f;
#pragma unroll 4
    for (int c = 0; c < NCH; ++c) {
        size_t idx = ((size_t)(b * NCH + c) * 16 + n) * 1024 + e;
        float p = PH[idx], s = S[idx];
        PH[idx] = H;
        H = p * H + s;
    }
}

// final sweep: y = sum_n C*h + u*D, gate with silu(z); emit pre-split bf16.
__global__ __launch_bounds__(256) void scan_stage3(
    const float* __restrict__ dtp, const float* __restrict__ u,
    const float* __restrict__ dbc,
    const void* __restrict__ alog, long aoff,
    const void* __restrict__ Dv, long doff,
    const int* __restrict__ flag,
    const float* __restrict__ xz, const float* __restrict__ H0,
    unsigned short* __restrict__ yh, unsigned short* __restrict__ yl)
{
    const int isbf = *flag;
    int g = blockIdx.x * 256 + threadIdx.x;   // 131072
    int e = g & 1023, c = (g >> 10) & (NCH - 1), b = g >> 16;
    int t0 = b * 1024 + c * CL;

    float dv[CL], uv[CL], zv[CL];
#pragma unroll
    for (int i = 0; i < CL; ++i) {
        dv[i] = dtp[(size_t)(t0 + i) * 1024 + e];
        uv[i] = u[(size_t)(t0 + i) * 1024 + e];
        zv[i] = xz[(size_t)(t0 + i) * 2048 + 1024 + e];
    }

    float Aen[16], h[16];
    size_t ob = ((size_t)(b * NCH + c) * 16) * 1024 + e;
#pragma unroll
    for (int n = 0; n < 16; ++n) {
        Aen[n] = -__expf(ldin(alog, aoff + e * 16 + n, isbf));
        h[n] = H0[ob + (size_t)n * 1024];
    }
    float De = ldin(Dv, doff + e, isbf);
#pragma unroll
    for (int i = 0; i < CL; ++i) {
        float d = dv[i], uu = uv[i], du = d * uu;
        const float4* Bp = (const float4*)(dbc + (size_t)(t0 + i) * 64 + 32);
        float4 b0 = Bp[0], b1 = Bp[1], b2 = Bp[2], b3 = Bp[3];
        float4 c0 = Bp[4], c1 = Bp[5], c2 = Bp[6], c3 = Bp[7];
        float Bt[16] = {b0.x,b0.y,b0.z,b0.w, b1.x,b1.y,b1.z,b1.w,
                        b2.x,b2.y,b2.z,b2.w, b3.x,b3.y,b3.z,b3.w};
        float Ct[16] = {c0.x,c0.y,c0.z,c0.w, c1.x,c1.y,c1.z,c1.w,
                        c2.x,c2.y,c2.z,c2.w, c3.x,c3.y,c3.z,c3.w};
        float y = 0.f;
#pragma unroll
        for (int n = 0; n < 16; ++n) {
            float a = __expf(d * Aen[n]);
            h[n] = a * h[n] + du * Bt[n];
            y += h[n] * Ct[n];
        }
        float sz = zv[i] / (1.f + __expf(-zv[i]));
        float yv = (y + uu * De) * sz;
        unsigned short hh, ll;
        split2(yv, hh, ll);
        yh[(size_t)(t0 + i) * 1024 + e] = hh;
        yl[(size_t)(t0 + i) * 1024 + e] = ll;
    }
}

// ------------------------------- launcher -----------------------------------
extern "C" void kernel_launch(void* const* d_in, const int* in_sizes, int n_in,
                              void* d_out, int out_size, void* d_ws, size_t ws_size,
                              hipStream_t stream)
{
    const void* x    = d_in[0];
    const void* pos  = d_in[1];
    const void* nw   = d_in[2];
    const void* ipw  = d_in[3];   // (6,2048,512)
    const void* cw   = d_in[4];   // (6,1024,4)
    const void* cb   = d_in[5];   // (6,1024)
    const void* xpw  = d_in[6];   // (6,64,1024)
    const void* dtw  = d_in[7];   // (6,1024,32)
    const void* dtb  = d_in[8];   // (6,1024)
    const void* alog = d_in[9];   // (6,1024,16)
    const void* Dw   = d_in[10];  // (6,1024)
    const void* ow   = d_in[11];  // (6,512,1024)

    char* w = (char*)d_ws;
    auto take = [&](size_t bytes) { char* p = w; w += (bytes + 255) & ~255ull; return p; };

    float* h    = (float*)take(2048ull * 512 * 4);
    float* xz   = (float*)take(2048ull * 2048 * 4);
    float* xi   = (float*)take(2048ull * 1024 * 4);
    float* dtf  = (float*)take(2048ull * 1024 * 4);
    float* dbc  = (float*)take(2048ull * 64 * 4);
    float* P    = (float*)take(2ull * NCH * 16 * 1024 * 4);   // 8 MB (also H0)
    float* S    = (float*)take(2ull * NCH * 16 * 1024 * 4);   // 8 MB
    float* Pxp  = (float*)take(8ull * 2048 * 64 * 4);
    unsigned short* xnh = (unsigned short*)take(2048ull * 512 * 2);
    unsigned short* xnl = (unsigned short*)take(2048ull * 512 * 2);
    unsigned short* xih = (unsigned short*)take(2048ull * 1024 * 2);
    unsigned short* xil = (unsigned short*)take(2048ull * 1024 * 2);
    unsigned short* yh  = (unsigned short*)take(2048ull * 1024 * 2);
    unsigned short* yl  = (unsigned short*)take(2048ull * 1024 * 2);
    unsigned short* dth = (unsigned short*)take(2048ull * 32 * 2);
    unsigned short* dtl = (unsigned short*)take(2048ull * 32 * 2);
    unsigned short* wip_h = (unsigned short*)take(6ull * 2048 * 512 * 2);
    unsigned short* wip_l = (unsigned short*)take(6ull * 2048 * 512 * 2);
    unsigned short* wow_h = (unsigned short*)take(6ull * 512 * 1024 * 2);
    unsigned short* wow_l = (unsigned short*)take(6ull * 512 * 1024 * 2);
    unsigned short* wxp_h = (unsigned short*)take(6ull * 64 * 1024 * 2);
    unsigned short* wxp_l = (unsigned short*)take(6ull * 64 * 1024 * 2);
    unsigned short* wdt_h = (unsigned short*)take(6ull * 1024 * 32 * 2);
    unsigned short* wdt_l = (unsigned short*)take(6ull * 1024 * 32 * 2);
    int* flag = (int*)take(256);

    dtype_probe<<<1, 1, 0, stream>>>(Dw, flag);
    cvt_in<<<4096, 256, 0, stream>>>(x, flag, h, 2048 * 512);
    wconv<<<24576, 256, 0, stream>>>(ipw, flag, wip_h, wip_l, 6 * 2048 * 512);
    wconv<<<12288, 256, 0, stream>>>(ow,  flag, wow_h, wow_l, 6 * 512 * 1024);
    wconv<<<1536, 256, 0, stream>>>(xpw, flag, wxp_h, wxp_l, 6 * 64 * 1024);
    wconv<<<768,  256, 0, stream>>>(dtw, flag, wdt_h, wdt_l, 6 * 1024 * 32);

    for (int l = 0; l < 6; ++l) {
        rmsnorm_k<<<2048, 256, 0, stream>>>(h, pos, nw, flag, xnh, xnl);
        gemm_hl<0><<<dim3(32, 32), 256, 0, stream>>>(
            xnh, xnl, 512, wip_h, wip_l, (long)l * 2048 * 512,
            xz, 0, nullptr, 0, flag, 2048, 512, 512);
        conv_silu_k<<<8192, 256, 0, stream>>>(xz, cw, (long)l * 4096, cb, (long)l * 1024,
                                              flag, xi, xih, xil);
        gemm_hl<0><<<dim3(32, 1, 8), 256, 0, stream>>>(
            xih, xil, 1024, wxp_h, wxp_l, (long)l * 64 * 1024,
            Pxp, 2048l * 64, nullptr, 0, flag, 64, 1024, 128);
        xp_reduce<<<512, 256, 0, stream>>>(Pxp, dbc, dth, dtl);
        gemm_hl<1><<<dim3(32, 16), 256, 0, stream>>>(
            dth, dtl, 32, wdt_h, wdt_l, (long)l * 1024 * 32,
            dtf, 0, dtb, (long)l * 1024, flag, 1024, 32, 32);
        scan_stage1<<<512, 256, 0, stream>>>(dtf, xi, dbc, alog, (long)l * 16384,
                                             flag, P, S);
        scan_stage2<<<128, 256, 0, stream>>>(P, S);
        scan_stage3<<<512, 256, 0, stream>>>(dtf, xi, dbc, alog, (long)l * 16384,
                                             Dw, (long)l * 1024, flag, xz, P, yh, yl);
        float* outp = (l < 5) ? h : (float*)d_out;
        gemm_hl<0><<<dim3(32, 8), 256, 0, stream>>>(
            yh, yl, 1024, wow_h, wow_l, (long)l * 512 * 1024,
            outp, 0, nullptr, 0, flag, 512, 1024, 1024);
    }
}

// Round 7
// 860.110 us; speedup vs baseline: 1.8556x; 1.0205x over previous
//
#include <hip/hip_runtime.h>
#include <hip/hip_bf16.h>

// ---------------------------------------------------------------------------
// Mamba encoder fwd: B=2, L=1024, D=512, E=1024, N=16, R=32, 6 layers.
// Inputs fp32 (probe-confirmed; dynamic dtype kept). Output fp32.
// GEMMs: split-bf16 (hi/lo, 3 MFMAs). in_proj uses 128x128 tile (LDS-read
// balanced, ~91% MFMA ratio); others 64x64. Weights pre-split once (1 kernel).
// Scan: chunked 64 x 16, lane axis = e, batch-preloaded operands; stage2
// batched 8-deep to hide load latency.
// ws_size = 256 MiB (fill-evidence); we use ~115 MB.
// ---------------------------------------------------------------------------

typedef __attribute__((ext_vector_type(8))) short bf16x8;
typedef __attribute__((ext_vector_type(4))) float f32x4;

__device__ __forceinline__ float bf2f(unsigned short u) {
    unsigned int x = ((unsigned int)u) << 16;
    return __builtin_bit_cast(float, x);
}
__device__ __forceinline__ unsigned short f2bf(float f) {
    __hip_bfloat16 h = __float2bfloat16(f);   // RNE
    return __builtin_bit_cast(unsigned short, h);
}
__device__ __forceinline__ float ldin(const void* p, size_t i, int isbf) {
    return isbf ? bf2f(((const unsigned short*)p)[i]) : ((const float*)p)[i];
}
__device__ __forceinline__ float softplus_f(float x) {
    return (x > 20.f) ? x : log1pf(__expf(x));
}
__device__ __forceinline__ void split2(float x, unsigned short& h, unsigned short& l) {
    h = f2bf(x);
    l = f2bf(x - bf2f(h));   // == 0 when x is exactly bf16
}

// --------- all-weights pre-split (+ dtype flag publish), one kernel ---------
#define S1 (6*2048*512)
#define S2 (6*512*1024)
#define S3 (6*64*1024)
#define S4 (6*1024*32)
__global__ __launch_bounds__(256) void wsplit_all(
    const void* __restrict__ ipw, const void* __restrict__ ow,
    const void* __restrict__ xpw, const void* __restrict__ dtw,
    const void* __restrict__ Dw,
    unsigned short* __restrict__ h1, unsigned short* __restrict__ l1,
    unsigned short* __restrict__ h2, unsigned short* __restrict__ l2,
    unsigned short* __restrict__ h3, unsigned short* __restrict__ l3,
    unsigned short* __restrict__ h4, unsigned short* __restrict__ l4,
    int* __restrict__ flag)
{
    int g = blockIdx.x * 256 + threadIdx.x;
    const int isbf = (*(const unsigned int*)Dw == 0x3F800000u) ? 0 : 1;
    if (g == 0) *flag = isbf;
    const void* src; unsigned short *dh, *dl; int i;
    if (g < S1)                { src = ipw; dh = h1; dl = l1; i = g; }
    else if (g < S1+S2)        { src = ow;  dh = h2; dl = l2; i = g - S1; }
    else if (g < S1+S2+S3)     { src = xpw; dh = h3; dl = l3; i = g - S1 - S2; }
    else if (g < S1+S2+S3+S4)  { src = dtw; dh = h4; dl = l4; i = g - S1 - S2 - S3; }
    else return;
    unsigned short hh, ll;
    split2(ldin(src, i, isbf), hh, ll);
    dh[i] = hh; dl[i] = ll;
}

// ------------------ GEMM 128x128 tile (in_proj): C = A * W^T ----------------
// A,W pre-split bf16 hi/lo.  BK=32, 256 threads (4 waves, 2x2, each 64x64).
__global__ __launch_bounds__(256) void gemm128(
    const unsigned short* __restrict__ Ah, const unsigned short* __restrict__ Al,
    int lda,
    const unsigned short* __restrict__ Wh, const unsigned short* __restrict__ Wl,
    long woff,
    float* __restrict__ Cf, int N, int K)
{
    __shared__ __align__(16) unsigned short As[2][128][40];
    __shared__ __align__(16) unsigned short Ws[2][128][40];

    const int m0 = blockIdx.x * 128, n0 = blockIdx.y * 128;
    const int t = threadIdx.x, lane = t & 63, wave = t >> 6;
    const int wm = (wave & 1) * 64, wn = (wave >> 1) * 64;
    const int srow = t >> 1, scol = (t & 1) * 16;

    const unsigned short* ah = Ah + (size_t)(m0 + srow) * lda + scol;
    const unsigned short* al = Al + (size_t)(m0 + srow) * lda + scol;
    const unsigned short* wh = Wh + woff + (size_t)(n0 + srow) * K + scol;
    const unsigned short* wl = Wl + woff + (size_t)(n0 + srow) * K + scol;

    f32x4 acc[4][4] = {};
    const int fm = lane & 15, fk = (lane >> 4) * 8;

    for (int k0 = 0; k0 < K; k0 += 32) {
        __syncthreads();
        *(uint4*)(&As[0][srow][scol])     = *(const uint4*)(ah + k0);
        *(uint4*)(&As[0][srow][scol + 8]) = *(const uint4*)(ah + k0 + 8);
        *(uint4*)(&As[1][srow][scol])     = *(const uint4*)(al + k0);
        *(uint4*)(&As[1][srow][scol + 8]) = *(const uint4*)(al + k0 + 8);
        *(uint4*)(&Ws[0][srow][scol])     = *(const uint4*)(wh + k0);
        *(uint4*)(&Ws[0][srow][scol + 8]) = *(const uint4*)(wh + k0 + 8);
        *(uint4*)(&Ws[1][srow][scol])     = *(const uint4*)(wl + k0);
        *(uint4*)(&Ws[1][srow][scol + 8]) = *(const uint4*)(wl + k0 + 8);
        __syncthreads();

        bf16x8 a_h[4], a_l[4], w_h[4], w_l[4];
#pragma unroll
        for (int i = 0; i < 4; ++i) {
            a_h[i] = *(const bf16x8*)(&As[0][wm + i * 16 + fm][fk]);
            a_l[i] = *(const bf16x8*)(&As[1][wm + i * 16 + fm][fk]);
            w_h[i] = *(const bf16x8*)(&Ws[0][wn + i * 16 + fm][fk]);
            w_l[i] = *(const bf16x8*)(&Ws[1][wn + i * 16 + fm][fk]);
        }
#pragma unroll
        for (int mi = 0; mi < 4; ++mi)
#pragma unroll
            for (int ni = 0; ni < 4; ++ni) {
                acc[mi][ni] = __builtin_amdgcn_mfma_f32_16x16x32_bf16(
                    a_h[mi], w_h[ni], acc[mi][ni], 0, 0, 0);
                acc[mi][ni] = __builtin_amdgcn_mfma_f32_16x16x32_bf16(
                    a_h[mi], w_l[ni], acc[mi][ni], 0, 0, 0);
                acc[mi][ni] = __builtin_amdgcn_mfma_f32_16x16x32_bf16(
                    a_l[mi], w_h[ni], acc[mi][ni], 0, 0, 0);
            }
    }

    const int col = lane & 15, rb = (lane >> 4) * 4;
#pragma unroll
    for (int mi = 0; mi < 4; ++mi)
#pragma unroll
        for (int ni = 0; ni < 4; ++ni)
#pragma unroll
            for (int r = 0; r < 4; ++r) {
                int gm = m0 + wm + mi * 16 + rb + r;
                int gn = n0 + wn + ni * 16 + col;
                Cf[(size_t)gm * N + gn] = acc[mi][ni][r];
            }
}

// ----------------------- GEMM 64x64 tile: C = A * W^T -----------------------
// Optional split-K via blockIdx.z.  acc += Ah*Wh + Ah*Wl + Al*Wh.
template <int ACT>
__global__ __launch_bounds__(256) void gemm_hl(
    const unsigned short* __restrict__ Ah, const unsigned short* __restrict__ Al,
    int lda,
    const unsigned short* __restrict__ Wh, const unsigned short* __restrict__ Wl,
    long woff,
    float* __restrict__ Cf, long zstride,
    const void* __restrict__ bias, long boff, const int* __restrict__ flag,
    int N, int K, int Kc)
{
    const int isbf = *flag;
    __shared__ __align__(16) unsigned short As[2][64][40];
    __shared__ __align__(16) unsigned short Ws[2][64][40];

    const int m0 = blockIdx.x * 64, n0 = blockIdx.y * 64;
    const int kb = blockIdx.z * Kc;
    const int t = threadIdx.x;
    const int lane = t & 63, wave = t >> 6;
    const int wm = (wave & 1) * 32, wn = (wave >> 1) * 32;
    const int srow = t >> 2, scol = (t & 3) * 8;

    const unsigned short* ah = Ah + (size_t)(m0 + srow) * lda + scol;
    const unsigned short* al = Al + (size_t)(m0 + srow) * lda + scol;
    const unsigned short* wh = Wh + woff + (size_t)(n0 + srow) * K + scol;
    const unsigned short* wl = Wl + woff + (size_t)(n0 + srow) * K + scol;

    f32x4 acc[2][2] = {};

    for (int k0 = kb; k0 < kb + Kc; k0 += 32) {
        __syncthreads();
        *(uint4*)(&As[0][srow][scol]) = *(const uint4*)(ah + k0);
        *(uint4*)(&As[1][srow][scol]) = *(const uint4*)(al + k0);
        *(uint4*)(&Ws[0][srow][scol]) = *(const uint4*)(wh + k0);
        *(uint4*)(&Ws[1][srow][scol]) = *(const uint4*)(wl + k0);
        __syncthreads();

        const int fm = lane & 15, fk = (lane >> 4) * 8;
        bf16x8 a0h = *(const bf16x8*)(&As[0][wm + fm][fk]);
        bf16x8 a1h = *(const bf16x8*)(&As[0][wm + 16 + fm][fk]);
        bf16x8 w0h = *(const bf16x8*)(&Ws[0][wn + fm][fk]);
        bf16x8 w1h = *(const bf16x8*)(&Ws[0][wn + 16 + fm][fk]);
        bf16x8 a0l = *(const bf16x8*)(&As[1][wm + fm][fk]);
        bf16x8 a1l = *(const bf16x8*)(&As[1][wm + 16 + fm][fk]);
        bf16x8 w0l = *(const bf16x8*)(&Ws[1][wn + fm][fk]);
        bf16x8 w1l = *(const bf16x8*)(&Ws[1][wn + 16 + fm][fk]);

        acc[0][0] = __builtin_amdgcn_mfma_f32_16x16x32_bf16(a0h, w0h, acc[0][0], 0, 0, 0);
        acc[0][1] = __builtin_amdgcn_mfma_f32_16x16x32_bf16(a0h, w1h, acc[0][1], 0, 0, 0);
        acc[1][0] = __builtin_amdgcn_mfma_f32_16x16x32_bf16(a1h, w0h, acc[1][0], 0, 0, 0);
        acc[1][1] = __builtin_amdgcn_mfma_f32_16x16x32_bf16(a1h, w1h, acc[1][1], 0, 0, 0);
        acc[0][0] = __builtin_amdgcn_mfma_f32_16x16x32_bf16(a0h, w0l, acc[0][0], 0, 0, 0);
        acc[0][1] = __builtin_amdgcn_mfma_f32_16x16x32_bf16(a0h, w1l, acc[0][1], 0, 0, 0);
        acc[1][0] = __builtin_amdgcn_mfma_f32_16x16x32_bf16(a1h, w0l, acc[1][0], 0, 0, 0);
        acc[1][1] = __builtin_amdgcn_mfma_f32_16x16x32_bf16(a1h, w1l, acc[1][1], 0, 0, 0);
        acc[0][0] = __builtin_amdgcn_mfma_f32_16x16x32_bf16(a0l, w0h, acc[0][0], 0, 0, 0);
        acc[0][1] = __builtin_amdgcn_mfma_f32_16x16x32_bf16(a0l, w1h, acc[0][1], 0, 0, 0);
        acc[1][0] = __builtin_amdgcn_mfma_f32_16x16x32_bf16(a1l, w0h, acc[1][0], 0, 0, 0);
        acc[1][1] = __builtin_amdgcn_mfma_f32_16x16x32_bf16(a1l, w1h, acc[1][1], 0, 0, 0);
    }

    float* Cp = Cf + (size_t)blockIdx.z * zstride;
    const int col = lane & 15, rb = (lane >> 4) * 4;
#pragma unroll
    for (int mi = 0; mi < 2; ++mi)
#pragma unroll
        for (int ni = 0; ni < 2; ++ni)
#pragma unroll
            for (int r = 0; r < 4; ++r) {
                int gm = m0 + wm + mi * 16 + rb + r;
                int gn = n0 + wn + ni * 16 + col;
                float v = acc[mi][ni][r];
                if (bias) v += ldin(bias, boff + gn, isbf);
                if (ACT == 1) v = softplus_f(v);
                Cp[(size_t)gm * N + gn] = v;
            }
}

// ------------- split-K reduce for x_proj + dt-operand pre-split -------------
__global__ __launch_bounds__(256) void xp_reduce(
    const float* __restrict__ Pxp, float* __restrict__ dbc,
    unsigned short* __restrict__ dth, unsigned short* __restrict__ dtl)
{
    int g = blockIdx.x * 256 + threadIdx.x;   // 131072 = 2048*64
    float s = 0.f;
#pragma unroll
    for (int z = 0; z < 8; ++z) s += Pxp[(size_t)z * 131072 + g];
    dbc[g] = s;
    int n = g & 63, t = g >> 6;
    if (n < 32) {
        unsigned short hh, ll;
        split2(s, hh, ll);
        dth[t * 32 + n] = hh; dtl[t * 32 + n] = ll;
    }
}

// ------------------- RMSNorm(h + pos) -> pre-split bf16 ---------------------
// hdyn=1: hsrc has the dynamic input dtype (layer 0, reads x); else fp32.
__global__ __launch_bounds__(256) void rmsnorm_k(
    const void* __restrict__ hsrc, int hdyn, const void* __restrict__ pos,
    const void* __restrict__ nw, const int* __restrict__ flag,
    unsigned short* __restrict__ xnh, unsigned short* __restrict__ xnl)
{
    const int isbf = *flag;
    const int row = blockIdx.x;
    const int t = threadIdx.x;
    const size_t base = (size_t)row * 512;
    float h0 = hdyn ? ldin(hsrc, base + t, isbf)       : ((const float*)hsrc)[base + t];
    float h1 = hdyn ? ldin(hsrc, base + 256 + t, isbf) : ((const float*)hsrc)[base + 256 + t];
    float v0 = h0 + ldin(pos, base + t, isbf);
    float v1 = h1 + ldin(pos, base + 256 + t, isbf);
    float ss = v0 * v0 + v1 * v1;
#pragma unroll
    for (int o = 32; o; o >>= 1) ss += __shfl_xor(ss, o, 64);
    __shared__ float sw[4];
    if ((t & 63) == 0) sw[t >> 6] = ss;
    __syncthreads();
    float tot = sw[0] + sw[1] + sw[2] + sw[3];
    float sc = rsqrtf(tot * (1.0f / 512.0f) + 1.1920929e-07f);
    float o0 = v0 * sc * ldin(nw, t, isbf);
    float o1 = v1 * sc * ldin(nw, 256 + t, isbf);
    unsigned short hh, ll;
    split2(o0, hh, ll); xnh[base + t] = hh;       xnl[base + t] = ll;
    split2(o1, hh, ll); xnh[base + 256 + t] = hh; xnl[base + 256 + t] = ll;
}

// ------- causal depthwise conv (k=4) + SiLU -> fp32 u + pre-split bf16 ------
__global__ __launch_bounds__(256) void conv_silu_k(
    const float* __restrict__ xz,
    const void* __restrict__ cw, long cwoff,
    const void* __restrict__ cb, long cboff,
    const int* __restrict__ flag,
    float* __restrict__ xi,
    unsigned short* __restrict__ xih, unsigned short* __restrict__ xil)
{
    const int isbf = *flag;
    int g = blockIdx.x * 256 + threadIdx.x;   // T*E = 2M
    int e = g & 1023;
    int l = (g >> 10) & 1023;
    int b = g >> 20;
    float acc = ldin(cb, cboff + e, isbf);
#pragma unroll
    for (int k = 0; k < 4; ++k) {
        int ls = l - 3 + k;
        if (ls >= 0)
            acc += ldin(cw, cwoff + e * 4 + k, isbf) *
                   xz[((size_t)(b * 1024 + ls)) * 2048 + e];
    }
    acc = acc / (1.f + __expf(-acc));         // SiLU
    xi[g] = acc;
    unsigned short hh, ll;
    split2(acc, hh, ll);
    xih[g] = hh; xil[g] = ll;
}

// --------------------- selective scan, chunked (64 x 16) --------------------
#define CL 16
#define NCH 64

__global__ __launch_bounds__(256) void scan_stage1(
    const float* __restrict__ dtp, const float* __restrict__ u,
    const float* __restrict__ dbc,
    const void* __restrict__ alog, long aoff, const int* __restrict__ flag,
    float* __restrict__ P, float* __restrict__ S)
{
    const int isbf = *flag;
    int g = blockIdx.x * 256 + threadIdx.x;   // 131072
    int e = g & 1023, c = (g >> 10) & (NCH - 1), b = g >> 16;
    int t0 = b * 1024 + c * CL;

    float dv[CL], uv[CL];
#pragma unroll
    for (int i = 0; i < CL; ++i) {
        dv[i] = dtp[(size_t)(t0 + i) * 1024 + e];
        uv[i] = u[(size_t)(t0 + i) * 1024 + e];
    }

    float Aen[16], Pn[16], Sn[16];
#pragma unroll
    for (int n = 0; n < 16; ++n) {
        Aen[n] = -__expf(ldin(alog, aoff + e * 16 + n, isbf));
        Pn[n] = 1.f; Sn[n] = 0.f;
    }
#pragma unroll
    for (int i = 0; i < CL; ++i) {
        float d = dv[i], du = d * uv[i];
        const float4* Bp = (const float4*)(dbc + (size_t)(t0 + i) * 64 + 32);
        float4 b0 = Bp[0], b1 = Bp[1], b2 = Bp[2], b3 = Bp[3];
        float Bt[16] = {b0.x,b0.y,b0.z,b0.w, b1.x,b1.y,b1.z,b1.w,
                        b2.x,b2.y,b2.z,b2.w, b3.x,b3.y,b3.z,b3.w};
#pragma unroll
        for (int n = 0; n < 16; ++n) {
            float a = __expf(d * Aen[n]);
            Sn[n] = a * Sn[n] + du * Bt[n];
            Pn[n] *= a;
        }
    }
    size_t ob = ((size_t)(b * NCH + c) * 16) * 1024 + e;
#pragma unroll
    for (int n = 0; n < 16; ++n) {
        P[ob + (size_t)n * 1024] = Pn[n];
        S[ob + (size_t)n * 1024] = Sn[n];
    }
}

// cross-chunk combine IN PLACE, 8-deep batched loads to hide latency.
__global__ __launch_bounds__(256) void scan_stage2(
    float* __restrict__ PH, const float* __restrict__ S)
{
    int g = blockIdx.x * 256 + threadIdx.x;   // 32768: e + 1024n + 16384b
    int e = g & 1023, n = (g >> 10) & 15, b = g >> 14;
    float H = 0.f;
    for (int cb = 0; cb < NCH; cb += 8) {
        float p[8], s[8];
#pragma unroll
        for (int j = 0; j < 8; ++j) {
            size_t idx = ((size_t)(b * NCH + cb + j) * 16 + n) * 1024 + e;
            p[j] = PH[idx]; s[j] = S[idx];
        }
#pragma unroll
        for (int j = 0; j < 8; ++j) {
            size_t idx = ((size_t)(b * NCH + cb + j) * 16 + n) * 1024 + e;
            PH[idx] = H;
            H = p[j] * H + s[j];
        }
    }
}

// final sweep: y = sum_n C*h + u*D, gate with silu(z); emit pre-split bf16.
__global__ __launch_bounds__(256) void scan_stage3(
    const float* __restrict__ dtp, const float* __restrict__ u,
    const float* __restrict__ dbc,
    const void* __restrict__ alog, long aoff,
    const void* __restrict__ Dv, long doff,
    const int* __restrict__ flag,
    const float* __restrict__ xz, const float* __restrict__ H0,
    unsigned short* __restrict__ yh, unsigned short* __restrict__ yl)
{
    const int isbf = *flag;
    int g = blockIdx.x * 256 + threadIdx.x;   // 131072
    int e = g & 1023, c = (g >> 10) & (NCH - 1), b = g >> 16;
    int t0 = b * 1024 + c * CL;

    float dv[CL], uv[CL], zv[CL];
#pragma unroll
    for (int i = 0; i < CL; ++i) {
        dv[i] = dtp[(size_t)(t0 + i) * 1024 + e];
        uv[i] = u[(size_t)(t0 + i) * 1024 + e];
        zv[i] = xz[(size_t)(t0 + i) * 2048 + 1024 + e];
    }

    float Aen[16], h[16];
    size_t ob = ((size_t)(b * NCH + c) * 16) * 1024 + e;
#pragma unroll
    for (int n = 0; n < 16; ++n) {
        Aen[n] = -__expf(ldin(alog, aoff + e * 16 + n, isbf));
        h[n] = H0[ob + (size_t)n * 1024];
    }
    float De = ldin(Dv, doff + e, isbf);
#pragma unroll
    for (int i = 0; i < CL; ++i) {
        float d = dv[i], uu = uv[i], du = d * uu;
        const float4* Bp = (const float4*)(dbc + (size_t)(t0 + i) * 64 + 32);
        float4 b0 = Bp[0], b1 = Bp[1], b2 = Bp[2], b3 = Bp[3];
        float4 c0 = Bp[4], c1 = Bp[5], c2 = Bp[6], c3 = Bp[7];
        float Bt[16] = {b0.x,b0.y,b0.z,b0.w, b1.x,b1.y,b1.z,b1.w,
                        b2.x,b2.y,b2.z,b2.w, b3.x,b3.y,b3.z,b3.w};
        float Ct[16] = {c0.x,c0.y,c0.z,c0.w, c1.x,c1.y,c1.z,c1.w,
                        c2.x,c2.y,c2.z,c2.w, c3.x,c3.y,c3.z,c3.w};
        float y = 0.f;
#pragma unroll
        for (int n = 0; n < 16; ++n) {
            float a = __expf(d * Aen[n]);
            h[n] = a * h[n] + du * Bt[n];
            y += h[n] * Ct[n];
        }
        float sz = zv[i] / (1.f + __expf(-zv[i]));
        float yv = (y + uu * De) * sz;
        unsigned short hh, ll;
        split2(yv, hh, ll);
        yh[(size_t)(t0 + i) * 1024 + e] = hh;
        yl[(size_t)(t0 + i) * 1024 + e] = ll;
    }
}

// ------------------------------- launcher -----------------------------------
extern "C" void kernel_launch(void* const* d_in, const int* in_sizes, int n_in,
                              void* d_out, int out_size, void* d_ws, size_t ws_size,
                              hipStream_t stream)
{
    const void* x    = d_in[0];
    const void* pos  = d_in[1];
    const void* nw   = d_in[2];
    const void* ipw  = d_in[3];   // (6,2048,512)
    const void* cw   = d_in[4];   // (6,1024,4)
    const void* cb   = d_in[5];   // (6,1024)
    const void* xpw  = d_in[6];   // (6,64,1024)
    const void* dtw  = d_in[7];   // (6,1024,32)
    const void* dtb  = d_in[8];   // (6,1024)
    const void* alog = d_in[9];   // (6,1024,16)
    const void* Dw   = d_in[10];  // (6,1024)
    const void* ow   = d_in[11];  // (6,512,1024)

    char* w = (char*)d_ws;
    auto take = [&](size_t bytes) { char* p = w; w += (bytes + 255) & ~255ull; return p; };

    float* h    = (float*)take(2048ull * 512 * 4);
    float* xz   = (float*)take(2048ull * 2048 * 4);
    float* xi   = (float*)take(2048ull * 1024 * 4);
    float* dtf  = (float*)take(2048ull * 1024 * 4);
    float* dbc  = (float*)take(2048ull * 64 * 4);
    float* P    = (float*)take(2ull * NCH * 16 * 1024 * 4);   // 8 MB (also H0)
    float* S    = (float*)take(2ull * NCH * 16 * 1024 * 4);   // 8 MB
    float* Pxp  = (float*)take(8ull * 2048 * 64 * 4);
    unsigned short* xnh = (unsigned short*)take(2048ull * 512 * 2);
    unsigned short* xnl = (unsigned short*)take(2048ull * 512 * 2);
    unsigned short* xih = (unsigned short*)take(2048ull * 1024 * 2);
    unsigned short* xil = (unsigned short*)take(2048ull * 1024 * 2);
    unsigned short* yh  = (unsigned short*)take(2048ull * 1024 * 2);
    unsigned short* yl  = (unsigned short*)take(2048ull * 1024 * 2);
    unsigned short* dth = (unsigned short*)take(2048ull * 32 * 2);
    unsigned short* dtl = (unsigned short*)take(2048ull * 32 * 2);
    unsigned short* wip_h = (unsigned short*)take(6ull * 2048 * 512 * 2);
    unsigned short* wip_l = (unsigned short*)take(6ull * 2048 * 512 * 2);
    unsigned short* wow_h = (unsigned short*)take(6ull * 512 * 1024 * 2);
    unsigned short* wow_l = (unsigned short*)take(6ull * 512 * 1024 * 2);
    unsigned short* wxp_h = (unsigned short*)take(6ull * 64 * 1024 * 2);
    unsigned short* wxp_l = (unsigned short*)take(6ull * 64 * 1024 * 2);
    unsigned short* wdt_h = (unsigned short*)take(6ull * 1024 * 32 * 2);
    unsigned short* wdt_l = (unsigned short*)take(6ull * 1024 * 32 * 2);
    int* flag = (int*)take(256);

    wsplit_all<<<(S1 + S2 + S3 + S4 + 255) / 256, 256, 0, stream>>>(
        ipw, ow, xpw, dtw, Dw,
        wip_h, wip_l, wow_h, wow_l, wxp_h, wxp_l, wdt_h, wdt_l, flag);

    for (int l = 0; l < 6; ++l) {
        // rmsnorm(h + pos): layer 0 reads x (dynamic dtype), else fp32 h
        rmsnorm_k<<<2048, 256, 0, stream>>>(
            l == 0 ? x : (const void*)h, l == 0 ? 1 : 0, pos, nw, flag, xnh, xnl);
        // in_proj: (T,512) x (2048,512)^T -> xz (T,2048), 128x128 tile
        gemm128<<<dim3(16, 16), 256, 0, stream>>>(
            xnh, xnl, 512, wip_h, wip_l, (long)l * 2048 * 512, xz, 2048, 512);
        conv_silu_k<<<8192, 256, 0, stream>>>(xz, cw, (long)l * 4096, cb, (long)l * 1024,
                                              flag, xi, xih, xil);
        // x_proj: (T,1024) x (64,1024)^T, split-K x8 -> Pxp, then reduce
        gemm_hl<0><<<dim3(32, 1, 8), 256, 0, stream>>>(
            xih, xil, 1024, wxp_h, wxp_l, (long)l * 64 * 1024,
            Pxp, 2048l * 64, nullptr, 0, flag, 64, 1024, 128);
        xp_reduce<<<512, 256, 0, stream>>>(Pxp, dbc, dth, dtl);
        // dt_proj: (T,32) x (1024,32)^T + dt_b, softplus -> dtf (T,1024)
        gemm_hl<1><<<dim3(32, 16), 256, 0, stream>>>(
            dth, dtl, 32, wdt_h, wdt_l, (long)l * 1024 * 32,
            dtf, 0, dtb, (long)l * 1024, flag, 1024, 32, 32);
        scan_stage1<<<512, 256, 0, stream>>>(dtf, xi, dbc, alog, (long)l * 16384,
                                             flag, P, S);
        scan_stage2<<<128, 256, 0, stream>>>(P, S);
        scan_stage3<<<512, 256, 0, stream>>>(dtf, xi, dbc, alog, (long)l * 16384,
                                             Dw, (long)l * 1024, flag, xz, P, yh, yl);
        // out_proj: (T,1024) x (512,1024)^T -> h (T,512); last layer -> d_out
        float* outp = (l < 5) ? h : (float*)d_out;
        gemm_hl<0><<<dim3(32, 8), 256, 0, stream>>>(
            yh, yl, 1024, wow_h, wow_l, (long)l * 512 * 1024,
            outp, 0, nullptr, 0, flag, 512, 1024, 1024);
    }
}